// Round 2
// baseline (567.124 us; speedup 1.0000x reference)
//
#include <hip/hip_runtime.h>
#include <stdint.h>

#define S_LEN 2048
#define NH    16
#define DK    64
#define DM    1024

typedef __attribute__((ext_vector_type(8))) __bf16 bf16x8;
typedef __attribute__((ext_vector_type(8))) unsigned short u16x8;
typedef __attribute__((ext_vector_type(4))) float  f32x4;

static __device__ __forceinline__ unsigned short f2bf(float f) {
    union { float f; unsigned int u; } v; v.f = f;
    unsigned int r = v.u + 0x7FFFu + ((v.u >> 16) & 1u);
    return (unsigned short)(r >> 16);
}

// exp(50*tanh(s/50)) without libcalls: u=2^(2s/50/ln2)=e^(2s/50); tanh=1-2/(u+1)
static __device__ __forceinline__ float cap_exp(float s) {
    float u = exp2f(s * 0.0577078016f);              // e^(2s/50)
    float t = 1.0f - 2.0f * __builtin_amdgcn_rcpf(u + 1.0f);   // tanh(s/50)
    return exp2f(t * 72.1347520444f);                // e^(50*tanh)
}

// ---------------------------------------------------------------------------
// Input dtype detector (fp32 low-halves have wild bf16 exponents).
// ---------------------------------------------------------------------------
__global__ void detect_f32(const unsigned short* __restrict__ x, int* __restrict__ flag)
{
    __shared__ int tot;
    if (threadIdx.x == 0) tot = 0;
    __syncthreads();
    int weird = 0;
    for (int i = threadIdx.x; i < 16384; i += 256) {
        int e = (x[i] >> 7) & 0xFF;
        if (e == 0 || e < 87 || e > 167) weird++;
    }
    atomicAdd(&tot, weird);
    __syncthreads();
    if (threadIdx.x == 0) *flag = (tot > 4000) ? 1 : 0;
}

// ---------------------------------------------------------------------------
// Normalize an input buffer to bf16 (copy if bf16, convert if fp32).
// ---------------------------------------------------------------------------
__global__ __launch_bounds__(256) void norm_bf16(const void* __restrict__ src,
                                                 unsigned short* __restrict__ dst,
                                                 int n, const int* __restrict__ flag)
{
    const int isf32 = *flag;
    int i = (blockIdx.x * 256 + threadIdx.x) * 8;
    if (i >= n) return;
    if (isf32) {
        const float* p = (const float*)src + i;
        u16x8 o;
        o[0] = f2bf(p[0]); o[1] = f2bf(p[1]); o[2] = f2bf(p[2]); o[3] = f2bf(p[3]);
        o[4] = f2bf(p[4]); o[5] = f2bf(p[5]); o[6] = f2bf(p[6]); o[7] = f2bf(p[7]);
        *(u16x8*)&dst[i] = o;
    } else {
        *(uint4*)&dst[i] = *(const uint4*)((const unsigned short*)src + i);
    }
}

#define LDSP 40   // padded K-stride for A/B staging (32 + 8)
#define VST  136  // padded s-stride for V transpose staging (128 + 8)

#define MFMA(a, b, c) __builtin_amdgcn_mfma_f32_16x16x32_bf16((a), (b), (c), 0, 0, 0)

// Shared GEMM mainloop: named accumulators — no local arrays (scratch-spill fix).
#define GEMM_MAIN(Aptr, Wptr, lda_, ldw_)                                              \
    f32x4 zz = {0.f, 0.f, 0.f, 0.f};                                                   \
    f32x4 c00=zz,c01=zz,c02=zz,c03=zz, c10=zz,c11=zz,c12=zz,c13=zz,                    \
          c20=zz,c21=zz,c22=zz,c23=zz, c30=zz,c31=zz,c32=zz,c33=zz;                    \
    for (int k0 = 0; k0 < 1024; k0 += 32) {                                            \
        __syncthreads();                                                               \
        {                                                                              \
            int row = tid >> 2, col = (tid & 3) << 3;                                  \
            *(bf16x8*)&As[row * LDSP + col] =                                          \
                *(const bf16x8*)&Aptr[(size_t)(m0 + row) * (lda_) + k0 + col];         \
            *(bf16x8*)&Bs[row * LDSP + col] =                                          \
                *(const bf16x8*)&Wptr[(size_t)(n0 + row) * (ldw_) + k0 + col];         \
            row += 64;                                                                 \
            *(bf16x8*)&As[row * LDSP + col] =                                          \
                *(const bf16x8*)&Aptr[(size_t)(m0 + row) * (lda_) + k0 + col];         \
            *(bf16x8*)&Bs[row * LDSP + col] =                                          \
                *(const bf16x8*)&Wptr[(size_t)(n0 + row) * (ldw_) + k0 + col];         \
        }                                                                              \
        __syncthreads();                                                               \
        bf16x8 a0 = *(const bf16x8*)&As[(wm +  0 + l16) * LDSP + quad * 8];            \
        bf16x8 a1 = *(const bf16x8*)&As[(wm + 16 + l16) * LDSP + quad * 8];            \
        bf16x8 a2 = *(const bf16x8*)&As[(wm + 32 + l16) * LDSP + quad * 8];            \
        bf16x8 a3 = *(const bf16x8*)&As[(wm + 48 + l16) * LDSP + quad * 8];            \
        bf16x8 b0 = *(const bf16x8*)&Bs[(wn +  0 + l16) * LDSP + quad * 8];            \
        bf16x8 b1 = *(const bf16x8*)&Bs[(wn + 16 + l16) * LDSP + quad * 8];            \
        bf16x8 b2 = *(const bf16x8*)&Bs[(wn + 32 + l16) * LDSP + quad * 8];            \
        bf16x8 b3 = *(const bf16x8*)&Bs[(wn + 48 + l16) * LDSP + quad * 8];            \
        c00 = MFMA(a0, b0, c00); c01 = MFMA(a0, b1, c01);                              \
        c02 = MFMA(a0, b2, c02); c03 = MFMA(a0, b3, c03);                              \
        c10 = MFMA(a1, b0, c10); c11 = MFMA(a1, b1, c11);                              \
        c12 = MFMA(a1, b2, c12); c13 = MFMA(a1, b3, c13);                              \
        c20 = MFMA(a2, b0, c20); c21 = MFMA(a2, b1, c21);                              \
        c22 = MFMA(a2, b2, c22); c23 = MFMA(a2, b3, c23);                              \
        c30 = MFMA(a3, b0, c30); c31 = MFMA(a3, b1, c31);                              \
        c32 = MFMA(a3, b2, c32); c33 = MFMA(a3, b3, c33);                              \
    }

// ---------------------------------------------------------------------------
// Fused QKV GEMM + RoPE/V-transpose epilogue.
// ---------------------------------------------------------------------------
__global__ __launch_bounds__(256) void gemm_fused(const unsigned short* __restrict__ A,
                                                  const unsigned short* __restrict__ W,
                                                  unsigned short* __restrict__ qr,
                                                  unsigned short* __restrict__ kr,
                                                  unsigned short* __restrict__ vt)
{
    __shared__ __align__(16) unsigned short smem[128 * VST]; // As/Bs union V-stage
    unsigned short* As = smem;
    unsigned short* Bs = smem + 128 * LDSP;

    const int tid  = threadIdx.x;
    const int wave = tid >> 6;
    const int lane = tid & 63;
    const int quad = lane >> 4;
    const int l16  = lane & 15;
    const int m0 = blockIdx.y * 128;
    const int n0 = blockIdx.x * 128;
    const int wm = (wave >> 1) * 64;
    const int wn = (wave & 1) * 64;

    GEMM_MAIN(A, W, 1024, 1024)

    const int cls = n0 >> 10;   // 0=Q, 1=K, 2=V  (block-uniform)
    if (cls < 2) {
        unsigned short* dst = cls ? kr : qr;
        const float qs = cls ? 1.0f : 0.125f;   // fold 1/sqrt(64) into q

#define ROPE_R(accv, MTc, rc, invf_, even_, h_, d_) do {                               \
        int row = m0 + wm + (MTc) * 16 + quad * 4 + (rc);                              \
        int s = row & (S_LEN - 1), b = row >> 11;                                      \
        float sn, cs;                                                                  \
        sincosf((float)s * (invf_), &sn, &cs);                                         \
        float own = accv[rc];                                                          \
        float oth = __shfl_xor(own, 1);                                                \
        float res = (even_) ? (own * cs - oth * sn) : (oth * sn + own * cs);           \
        dst[((size_t)(b * NH + (h_)) * S_LEN + s) * DK + (d_)] = f2bf(res * qs);       \
    } while (0)

#define ROPE_ST(accv, MTc, NTc) do {                                                   \
        int col = (n0 & 1023) + wn + (NTc) * 16 + l16;                                 \
        int h = col >> 6, d = col & 63;                                                \
        float invf = exp2f(-(float)(d >> 1) * 0.41524101186f);                         \
        int even = !(d & 1);                                                           \
        ROPE_R(accv, MTc, 0, invf, even, h, d);                                        \
        ROPE_R(accv, MTc, 1, invf, even, h, d);                                        \
        ROPE_R(accv, MTc, 2, invf, even, h, d);                                        \
        ROPE_R(accv, MTc, 3, invf, even, h, d);                                        \
    } while (0)

        ROPE_ST(c00, 0, 0); ROPE_ST(c01, 0, 1); ROPE_ST(c02, 0, 2); ROPE_ST(c03, 0, 3);
        ROPE_ST(c10, 1, 0); ROPE_ST(c11, 1, 1); ROPE_ST(c12, 1, 2); ROPE_ST(c13, 1, 3);
        ROPE_ST(c20, 2, 0); ROPE_ST(c21, 2, 1); ROPE_ST(c22, 2, 2); ROPE_ST(c23, 2, 3);
        ROPE_ST(c30, 3, 0); ROPE_ST(c31, 3, 1); ROPE_ST(c32, 3, 2); ROPE_ST(c33, 3, 3);
    } else {
        __syncthreads();   // As/Bs done; reuse smem as vstage[d][s], stride VST

#define VST_ACC(accv, MTc, NTc) do {                                                   \
        int dl = wn + (NTc) * 16 + l16;                                                \
        int base = dl * VST + wm + (MTc) * 16 + quad * 4;                              \
        smem[base + 0] = f2bf(accv[0]); smem[base + 1] = f2bf(accv[1]);                \
        smem[base + 2] = f2bf(accv[2]); smem[base + 3] = f2bf(accv[3]);                \
    } while (0)

        VST_ACC(c00, 0, 0); VST_ACC(c01, 0, 1); VST_ACC(c02, 0, 2); VST_ACC(c03, 0, 3);
        VST_ACC(c10, 1, 0); VST_ACC(c11, 1, 1); VST_ACC(c12, 1, 2); VST_ACC(c13, 1, 3);
        VST_ACC(c20, 2, 0); VST_ACC(c21, 2, 1); VST_ACC(c22, 2, 2); VST_ACC(c23, 2, 3);
        VST_ACC(c30, 3, 0); VST_ACC(c31, 3, 1); VST_ACC(c32, 3, 2); VST_ACC(c33, 3, 3);
        __syncthreads();
        int dl = tid >> 1, sh = (tid & 1) * 64;
        int vcol = (n0 - 2048) + dl;          // 0..1023
        int h = vcol >> 6, dd = vcol & 63;
        int b = m0 >> 11, s0 = m0 & (S_LEN - 1);
        unsigned short* dst = vt + (((size_t)(b * NH + h) * DK + dd) * S_LEN + s0 + sh);
        const unsigned short* src = smem + dl * VST + sh;
#pragma unroll
        for (int i = 0; i < 64; i += 8)
            *(bf16x8*)&dst[i] = *(const bf16x8*)&src[i];
    }
}

// ---------------------------------------------------------------------------
// Out projection GEMM: C_fp32 = A_bf16 @ W_bf16^T.
// ---------------------------------------------------------------------------
__global__ __launch_bounds__(256) void gemm_out(const unsigned short* __restrict__ A,
                                                const unsigned short* __restrict__ W,
                                                float* __restrict__ C)
{
    __shared__ __align__(16) unsigned short As[128 * LDSP];
    __shared__ __align__(16) unsigned short Bs[128 * LDSP];
    const int tid  = threadIdx.x;
    const int wave = tid >> 6;
    const int lane = tid & 63;
    const int quad = lane >> 4;
    const int l16  = lane & 15;
    const int m0 = blockIdx.y * 128;
    const int n0 = blockIdx.x * 128;
    const int wm = (wave >> 1) * 64;
    const int wn = (wave & 1) * 64;

    GEMM_MAIN(A, W, 1024, 1024)

#define OUT_ST(accv, MTc, NTc) do {                                                    \
    int col = n0 + wn + (NTc) * 16 + l16;                                              \
    int rowb = m0 + wm + (MTc) * 16 + quad * 4;                                        \
    C[(size_t)(rowb + 0) * 1024 + col] = accv[0];                                      \
    C[(size_t)(rowb + 1) * 1024 + col] = accv[1];                                      \
    C[(size_t)(rowb + 2) * 1024 + col] = accv[2];                                      \
    C[(size_t)(rowb + 3) * 1024 + col] = accv[3];                                      \
} while (0)

    OUT_ST(c00, 0, 0); OUT_ST(c01, 0, 1); OUT_ST(c02, 0, 2); OUT_ST(c03, 0, 3);
    OUT_ST(c10, 1, 0); OUT_ST(c11, 1, 1); OUT_ST(c12, 1, 2); OUT_ST(c13, 1, 3);
    OUT_ST(c20, 2, 0); OUT_ST(c21, 2, 1); OUT_ST(c22, 2, 2); OUT_ST(c23, 2, 3);
    OUT_ST(c30, 3, 0); OUT_ST(c31, 3, 1); OUT_ST(c32, 3, 2); OUT_ST(c33, 3, 3);
}

// ---------------------------------------------------------------------------
// Flash attention, causal, soft-cap 50*tanh(s/50).
// Soft-cap bounds scores -> no online max / rescale (validated earlier).
// One wave = 16 q rows; 64-key chunks; per-wave P buffer in LDS.
//
// ROUND 0: causal load balance — block p handles qblk p AND 31-p (33 chunks).
// ROUND 1: (a) XCD swizzle: 16 blocks sharing one bh's K/V (512 KB) land on
//   ONE XCD -> 8 bh x 512 KB = 4 MB = L2 size per XCD (was: all 32 bh thrash
//   every L2, FETCH 260 MB). (b) K-register prefetch for chunk c+1 issued
//   after V(c) loads -> doubles outstanding bytes/wave (Little's law: was
//   256 B in flight @ ~500 cy = 1.1 TB/s observed). (c) causal-mask compares
//   peeled to the diagonal chunk only. __launch_bounds__(256,4) keeps
//   VGPR<=128 so 4 blocks/CU stay resident.
// ---------------------------------------------------------------------------
#define PPL 72   // P-row stride in LDS (64 keys + 8 pad)

__global__ __launch_bounds__(256, 4) void attn_fwd(const unsigned short* __restrict__ qr,
                                                   const unsigned short* __restrict__ kr,
                                                   const unsigned short* __restrict__ vt,
                                                   unsigned short* __restrict__ aout)
{
    __shared__ __align__(16) unsigned short plds[4][16 * PPL];
    // XCD-aware swizzle: 1024 blocks, 8 XCDs, 128 blocks/XCD (bijective).
    int bid  = blockIdx.x;
    int blk  = (bid & 7) * 128 + (bid >> 3);
    int pr   = blk & 15;
    int bh   = blk >> 4;
    int b    = bh >> 4, h = bh & 15;
    int wave = threadIdx.x >> 6;
    int lane = threadIdx.x & 63;
    int quad = lane >> 4, l16 = lane & 15;

    const unsigned short* kbase = kr + (size_t)bh * S_LEN * DK;
    const unsigned short* vbase = vt + (size_t)bh * DK * S_LEN;
    unsigned short* pw = &plds[wave][0];

#define KLOAD(p_) do {                                                                 \
    ka0 = *(const bf16x8*)(p_);             kb0 = *(const bf16x8*)((p_) + 32);         \
    ka1 = *(const bf16x8*)((p_) + 16 * DK); kb1 = *(const bf16x8*)((p_) + 16 * DK + 32);\
    ka2 = *(const bf16x8*)((p_) + 32 * DK); kb2 = *(const bf16x8*)((p_) + 32 * DK + 32);\
    ka3 = *(const bf16x8*)((p_) + 48 * DK); kb3 = *(const bf16x8*)((p_) + 48 * DK + 32);\
} while (0)

#define QK_MFMA() do {                                                                 \
    sc0 = MFMA(qf0, ka0, sc0); sc0 = MFMA(qf1, kb0, sc0);                              \
    sc1 = MFMA(qf0, ka1, sc1); sc1 = MFMA(qf1, kb1, sc1);                              \
    sc2 = MFMA(qf0, ka2, sc2); sc2 = MFMA(qf1, kb2, sc2);                              \
    sc3 = MFMA(qf0, ka3, sc3); sc3 = MFMA(qf1, kb3, sc3);                              \
} while (0)

#define VLOAD_DECL(j0_)                                                                \
    const unsigned short* vp = vbase + (size_t)l16 * S_LEN + (j0_) + quad * 8;         \
    bf16x8 v00 = *(const bf16x8*)(vp);                                                 \
    bf16x8 v01 = *(const bf16x8*)(vp + 32);                                            \
    bf16x8 v10 = *(const bf16x8*)(vp + 16 * S_LEN);                                    \
    bf16x8 v11 = *(const bf16x8*)(vp + 16 * S_LEN + 32);                               \
    bf16x8 v20 = *(const bf16x8*)(vp + 32 * S_LEN);                                    \
    bf16x8 v21 = *(const bf16x8*)(vp + 32 * S_LEN + 32);                               \
    bf16x8 v30 = *(const bf16x8*)(vp + 48 * S_LEN);                                    \
    bf16x8 v31 = *(const bf16x8*)(vp + 48 * S_LEN + 32);

// unmasked softmax row update (non-diagonal chunks)
#define ROW_UPD_N(rc) do {                                                             \
    float p0 = cap_exp(sc0[rc]);                                                       \
    float p1 = cap_exp(sc1[rc]);                                                       \
    float p2 = cap_exp(sc2[rc]);                                                       \
    float p3 = cap_exp(sc3[rc]);                                                       \
    l##rc += (p0 + p1) + (p2 + p3);                                                    \
    int rb = (quad * 4 + (rc)) * PPL + l16;                                            \
    pw[rb]      = f2bf(p0);                                                            \
    pw[rb + 16] = f2bf(p1);                                                            \
    pw[rb + 32] = f2bf(p2);                                                            \
    pw[rb + 48] = f2bf(p3);                                                            \
} while (0)

// masked softmax row update (diagonal chunk only)
#define ROW_UPD_M(rc) do {                                                             \
    int qrow = q0w + quad * 4 + (rc);                                                  \
    float p0 = (j0 + l16      > qrow) ? 0.f : cap_exp(sc0[rc]);                        \
    float p1 = (j0 + 16 + l16 > qrow) ? 0.f : cap_exp(sc1[rc]);                        \
    float p2 = (j0 + 32 + l16 > qrow) ? 0.f : cap_exp(sc2[rc]);                        \
    float p3 = (j0 + 48 + l16 > qrow) ? 0.f : cap_exp(sc3[rc]);                        \
    l##rc += (p0 + p1) + (p2 + p3);                                                    \
    int rb = (quad * 4 + (rc)) * PPL + l16;                                            \
    pw[rb]      = f2bf(p0);                                                            \
    pw[rb + 16] = f2bf(p1);                                                            \
    pw[rb + 32] = f2bf(p2);                                                            \
    pw[rb + 48] = f2bf(p3);                                                            \
} while (0)

#define PV_MFMA() do {                                                                 \
    bf16x8 pf0 = *(const bf16x8*)&pw[l16 * PPL + quad * 8];                            \
    bf16x8 pf1 = *(const bf16x8*)&pw[l16 * PPL + 32 + quad * 8];                       \
    o0 = MFMA(pf0, v00, o0); o0 = MFMA(pf1, v01, o0);                                  \
    o1 = MFMA(pf0, v10, o1); o1 = MFMA(pf1, v11, o1);                                  \
    o2 = MFMA(pf0, v20, o2); o2 = MFMA(pf1, v21, o2);                                  \
    o3 = MFMA(pf0, v30, o3); o3 = MFMA(pf1, v31, o3);                                  \
} while (0)

    for (int side = 0; side < 2; ++side) {
        const int qblk = side ? (31 - pr) : pr;   // pairs sum to 33 chunks
        const int q0w  = qblk * 64 + wave * 16;

        const unsigned short* qbase = qr + ((size_t)bh * S_LEN + q0w) * DK;
        bf16x8 qf0 = *(const bf16x8*)&qbase[l16 * DK + quad * 8];
        bf16x8 qf1 = *(const bf16x8*)&qbase[l16 * DK + 32 + quad * 8];

        f32x4 zz = {0.f, 0.f, 0.f, 0.f};
        f32x4 o0 = zz, o1 = zz, o2 = zz, o3 = zz;
        float l0 = 0.f, l1 = 0.f, l2 = 0.f, l3 = 0.f;

        const int nch = qblk + 1;   // 64-key chunks; uniform across the block

        // K for chunk 0 (prologue)
        bf16x8 ka0, kb0, ka1, kb1, ka2, kb2, ka3, kb3;
        const unsigned short* kptr = kbase + (size_t)l16 * DK + quad * 8;
        KLOAD(kptr);

        // ---- unmasked chunks 0 .. nch-2 (K for c+1 prefetched in-loop) ----
        for (int c = 0; c < nch - 1; ++c) {
            const int j0 = c * 64;
            f32x4 sc0 = zz, sc1 = zz, sc2 = zz, sc3 = zz;
            QK_MFMA();
            // V(c) issued BEFORE the K-prefetch so PV's vmcnt wait leaves
            // next-chunk K in flight across softmax+PV.
            VLOAD_DECL(j0);
            kptr += 64 * DK;
            KLOAD(kptr);
            ROW_UPD_N(0); ROW_UPD_N(1); ROW_UPD_N(2); ROW_UPD_N(3);
            asm volatile("s_waitcnt lgkmcnt(0)" ::: "memory");
            PV_MFMA();
        }

        // ---- diagonal chunk (c = nch-1), K already in registers ----
        {
            const int j0 = (nch - 1) * 64;
            f32x4 sc0 = zz, sc1 = zz, sc2 = zz, sc3 = zz;
            QK_MFMA();
            VLOAD_DECL(j0);
            ROW_UPD_M(0); ROW_UPD_M(1); ROW_UPD_M(2); ROW_UPD_M(3);
            asm volatile("s_waitcnt lgkmcnt(0)" ::: "memory");
            PV_MFMA();
        }

        // ---- deferred l reduction (16 lanes within quad) + output ----
#define OUT_ROW(rc) do {                                                               \
        float lr = l##rc;                                                              \
        lr += __shfl_xor(lr, 1); lr += __shfl_xor(lr, 2);                              \
        lr += __shfl_xor(lr, 4); lr += __shfl_xor(lr, 8);                              \
        int qrow = q0w + quad * 4 + (rc);                                              \
        size_t off = (size_t)(b * S_LEN + qrow) * DM + h * DK + l16;                   \
        float rl = 1.0f / lr;                                                          \
        aout[off +  0] = f2bf(o0[rc] * rl);                                            \
        aout[off + 16] = f2bf(o1[rc] * rl);                                            \
        aout[off + 32] = f2bf(o2[rc] * rl);                                            \
        aout[off + 48] = f2bf(o3[rc] * rl);                                            \
} while (0)

        OUT_ROW(0); OUT_ROW(1); OUT_ROW(2); OUT_ROW(3);
#undef OUT_ROW
    }
}

// ---------------------------------------------------------------------------
extern "C" void kernel_launch(void* const* d_in, const int* in_sizes, int n_in,
                              void* d_out, int out_size, void* d_ws, size_t ws_size,
                              hipStream_t stream)
{
    // identify inputs by element count (robust to ordering)
    const void* x = nullptr; const void* wqkv = nullptr; const void* wout = nullptr;
    for (int i = 0; i < n_in; ++i) {
        if      (in_sizes[i] == 8388608) x    = d_in[i];   // [4,2048,1024]
        else if (in_sizes[i] == 3145728) wqkv = d_in[i];   // [3072,1024]
        else if (in_sizes[i] == 1048576) wout = d_in[i];   // [1024,1024]
    }
    float* out = (float*)d_out;                      // [4,2048,1024] fp32
    unsigned short* ws   = (unsigned short*)d_ws;
    unsigned short* ob16 = (unsigned short*)d_out;   // d_out viewed as bf16 scratch

    // ws (48 MiB + 4 B): qr | kr | aout slots of 8,388,608 bf16 elems each.
    unsigned short* qr     = ws;
    unsigned short* kr     = ws + (size_t)8388608;
    unsigned short* aout   = ws + (size_t)16777216;
    int* flag              = (int*)(ws + (size_t)25165824);
    unsigned short* wqkvbf = aout;   // staged in aout slot; dead before attn writes
    unsigned short* woutbf = qr;     // staged in qr slot AFTER attn (qr then dead)

    // d_out bf16 view: vt [0, 8.4M) | xbf [8.4M, 16.8M); both dead before
    // gemm_out overwrites d_out with fp32 results.
    unsigned short* vt  = ob16;
    unsigned short* xbf = ob16 + (size_t)8388608;

    // 0) input dtype autodetect (bf16 expected; fp32 tolerated)
    detect_f32<<<1, 256, 0, stream>>>((const unsigned short*)x, flag);
    // 1) normalize x and w_qkv to bf16
    norm_bf16<<<4096, 256, 0, stream>>>(x, xbf, 8388608, flag);
    norm_bf16<<<1536, 256, 0, stream>>>(wqkv, wqkvbf, 3145728, flag);
    // 2) fused: qkv GEMM + RoPE(q,k) -> qr/kr [b,h,s,d] (q/8), v -> vt [b,h,d,s]
    gemm_fused<<<dim3(24, 64), 256, 0, stream>>>(xbf, wqkvbf, qr, kr, vt);
    // 3) causal soft-capped flash attention (balanced + XCD-local + prefetch)
    attn_fwd<<<1024, 256, 0, stream>>>(qr, kr, vt, aout);
    // 4) normalize w_out into the now-dead qr slot
    norm_bf16<<<512, 256, 0, stream>>>(wout, woutbf, 1048576, flag);
    // 5) out_fp32 = aout @ w_out^T  (M=8192, N=1024, K=1024)
    gemm_out<<<dim3(8, 64), 256, 0, stream>>>(aout, woutbf, out);
}

// Round 3
// 550.184 us; speedup vs baseline: 1.0308x; 1.0308x over previous
//
#include <hip/hip_runtime.h>
#include <stdint.h>

#define S_LEN 2048
#define NH    16
#define DK    64
#define DM    1024

typedef __attribute__((ext_vector_type(8))) __bf16 bf16x8;
typedef __attribute__((ext_vector_type(8))) unsigned short u16x8;
typedef __attribute__((ext_vector_type(4))) float  f32x4;

static __device__ __forceinline__ unsigned short f2bf(float f) {
    union { float f; unsigned int u; } v; v.f = f;
    unsigned int r = v.u + 0x7FFFu + ((v.u >> 16) & 1u);
    return (unsigned short)(r >> 16);
}

// exp(50*tanh(s/50)) without libcalls: u=2^(2s/50/ln2)=e^(2s/50); tanh=1-2/(u+1)
static __device__ __forceinline__ float cap_exp(float s) {
    float u = exp2f(s * 0.0577078016f);              // e^(2s/50)
    float t = 1.0f - 2.0f * __builtin_amdgcn_rcpf(u + 1.0f);   // tanh(s/50)
    return exp2f(t * 72.1347520444f);                // e^(50*tanh)
}

// ---------------------------------------------------------------------------
// Input dtype detector (fp32 low-halves have wild bf16 exponents).
// ---------------------------------------------------------------------------
__global__ void detect_f32(const unsigned short* __restrict__ x, int* __restrict__ flag)
{
    __shared__ int tot;
    if (threadIdx.x == 0) tot = 0;
    __syncthreads();
    int weird = 0;
    for (int i = threadIdx.x; i < 16384; i += 256) {
        int e = (x[i] >> 7) & 0xFF;
        if (e == 0 || e < 87 || e > 167) weird++;
    }
    atomicAdd(&tot, weird);
    __syncthreads();
    if (threadIdx.x == 0) *flag = (tot > 4000) ? 1 : 0;
}

// ---------------------------------------------------------------------------
// Normalize an input buffer to bf16 (copy if bf16, convert if fp32).
// ---------------------------------------------------------------------------
__global__ __launch_bounds__(256) void norm_bf16(const void* __restrict__ src,
                                                 unsigned short* __restrict__ dst,
                                                 int n, const int* __restrict__ flag)
{
    const int isf32 = *flag;
    int i = (blockIdx.x * 256 + threadIdx.x) * 8;
    if (i >= n) return;
    if (isf32) {
        const float* p = (const float*)src + i;
        u16x8 o;
        o[0] = f2bf(p[0]); o[1] = f2bf(p[1]); o[2] = f2bf(p[2]); o[3] = f2bf(p[3]);
        o[4] = f2bf(p[4]); o[5] = f2bf(p[5]); o[6] = f2bf(p[6]); o[7] = f2bf(p[7]);
        *(u16x8*)&dst[i] = o;
    } else {
        *(uint4*)&dst[i] = *(const uint4*)((const unsigned short*)src + i);
    }
}

#define LDSP 40   // padded K-stride for A/B staging (32 + 8)
#define VST  136  // padded s-stride for V transpose staging (128 + 8)

#define MFMA(a, b, c) __builtin_amdgcn_mfma_f32_16x16x32_bf16((a), (b), (c), 0, 0, 0)

// Shared GEMM mainloop: named accumulators — no local arrays (scratch-spill fix).
#define GEMM_MAIN(Aptr, Wptr, lda_, ldw_)                                              \
    f32x4 zz = {0.f, 0.f, 0.f, 0.f};                                                   \
    f32x4 c00=zz,c01=zz,c02=zz,c03=zz, c10=zz,c11=zz,c12=zz,c13=zz,                    \
          c20=zz,c21=zz,c22=zz,c23=zz, c30=zz,c31=zz,c32=zz,c33=zz;                    \
    for (int k0 = 0; k0 < 1024; k0 += 32) {                                            \
        __syncthreads();                                                               \
        {                                                                              \
            int row = tid >> 2, col = (tid & 3) << 3;                                  \
            *(bf16x8*)&As[row * LDSP + col] =                                          \
                *(const bf16x8*)&Aptr[(size_t)(m0 + row) * (lda_) + k0 + col];         \
            *(bf16x8*)&Bs[row * LDSP + col] =                                          \
                *(const bf16x8*)&Wptr[(size_t)(n0 + row) * (ldw_) + k0 + col];         \
            row += 64;                                                                 \
            *(bf16x8*)&As[row * LDSP + col] =                                          \
                *(const bf16x8*)&Aptr[(size_t)(m0 + row) * (lda_) + k0 + col];         \
            *(bf16x8*)&Bs[row * LDSP + col] =                                          \
                *(const bf16x8*)&Wptr[(size_t)(n0 + row) * (ldw_) + k0 + col];         \
        }                                                                              \
        __syncthreads();                                                               \
        bf16x8 a0 = *(const bf16x8*)&As[(wm +  0 + l16) * LDSP + quad * 8];            \
        bf16x8 a1 = *(const bf16x8*)&As[(wm + 16 + l16) * LDSP + quad * 8];            \
        bf16x8 a2 = *(const bf16x8*)&As[(wm + 32 + l16) * LDSP + quad * 8];            \
        bf16x8 a3 = *(const bf16x8*)&As[(wm + 48 + l16) * LDSP + quad * 8];            \
        bf16x8 b0 = *(const bf16x8*)&Bs[(wn +  0 + l16) * LDSP + quad * 8];            \
        bf16x8 b1 = *(const bf16x8*)&Bs[(wn + 16 + l16) * LDSP + quad * 8];            \
        bf16x8 b2 = *(const bf16x8*)&Bs[(wn + 32 + l16) * LDSP + quad * 8];            \
        bf16x8 b3 = *(const bf16x8*)&Bs[(wn + 48 + l16) * LDSP + quad * 8];            \
        c00 = MFMA(a0, b0, c00); c01 = MFMA(a0, b1, c01);                              \
        c02 = MFMA(a0, b2, c02); c03 = MFMA(a0, b3, c03);                              \
        c10 = MFMA(a1, b0, c10); c11 = MFMA(a1, b1, c11);                              \
        c12 = MFMA(a1, b2, c12); c13 = MFMA(a1, b3, c13);                              \
        c20 = MFMA(a2, b0, c20); c21 = MFMA(a2, b1, c21);                              \
        c22 = MFMA(a2, b2, c22); c23 = MFMA(a2, b3, c23);                              \
        c30 = MFMA(a3, b0, c30); c31 = MFMA(a3, b1, c31);                              \
        c32 = MFMA(a3, b2, c32); c33 = MFMA(a3, b3, c33);                              \
    }

// ---------------------------------------------------------------------------
// Fused QKV GEMM + RoPE/V-transpose epilogue.
// ---------------------------------------------------------------------------
__global__ __launch_bounds__(256) void gemm_fused(const unsigned short* __restrict__ A,
                                                  const unsigned short* __restrict__ W,
                                                  unsigned short* __restrict__ qr,
                                                  unsigned short* __restrict__ kr,
                                                  unsigned short* __restrict__ vt)
{
    __shared__ __align__(16) unsigned short smem[128 * VST]; // As/Bs union V-stage
    unsigned short* As = smem;
    unsigned short* Bs = smem + 128 * LDSP;

    const int tid  = threadIdx.x;
    const int wave = tid >> 6;
    const int lane = tid & 63;
    const int quad = lane >> 4;
    const int l16  = lane & 15;
    const int m0 = blockIdx.y * 128;
    const int n0 = blockIdx.x * 128;
    const int wm = (wave >> 1) * 64;
    const int wn = (wave & 1) * 64;

    GEMM_MAIN(A, W, 1024, 1024)

    const int cls = n0 >> 10;   // 0=Q, 1=K, 2=V  (block-uniform)
    if (cls < 2) {
        unsigned short* dst = cls ? kr : qr;
        const float qs = cls ? 1.0f : 0.125f;   // fold 1/sqrt(64) into q

#define ROPE_R(accv, MTc, rc, invf_, even_, h_, d_) do {                               \
        int row = m0 + wm + (MTc) * 16 + quad * 4 + (rc);                              \
        int s = row & (S_LEN - 1), b = row >> 11;                                      \
        float sn, cs;                                                                  \
        sincosf((float)s * (invf_), &sn, &cs);                                         \
        float own = accv[rc];                                                          \
        float oth = __shfl_xor(own, 1);                                                \
        float res = (even_) ? (own * cs - oth * sn) : (oth * sn + own * cs);           \
        dst[((size_t)(b * NH + (h_)) * S_LEN + s) * DK + (d_)] = f2bf(res * qs);       \
    } while (0)

#define ROPE_ST(accv, MTc, NTc) do {                                                   \
        int col = (n0 & 1023) + wn + (NTc) * 16 + l16;                                 \
        int h = col >> 6, d = col & 63;                                                \
        float invf = exp2f(-(float)(d >> 1) * 0.41524101186f);                         \
        int even = !(d & 1);                                                           \
        ROPE_R(accv, MTc, 0, invf, even, h, d);                                        \
        ROPE_R(accv, MTc, 1, invf, even, h, d);                                        \
        ROPE_R(accv, MTc, 2, invf, even, h, d);                                        \
        ROPE_R(accv, MTc, 3, invf, even, h, d);                                        \
    } while (0)

        ROPE_ST(c00, 0, 0); ROPE_ST(c01, 0, 1); ROPE_ST(c02, 0, 2); ROPE_ST(c03, 0, 3);
        ROPE_ST(c10, 1, 0); ROPE_ST(c11, 1, 1); ROPE_ST(c12, 1, 2); ROPE_ST(c13, 1, 3);
        ROPE_ST(c20, 2, 0); ROPE_ST(c21, 2, 1); ROPE_ST(c22, 2, 2); ROPE_ST(c23, 2, 3);
        ROPE_ST(c30, 3, 0); ROPE_ST(c31, 3, 1); ROPE_ST(c32, 3, 2); ROPE_ST(c33, 3, 3);
    } else {
        __syncthreads();   // As/Bs done; reuse smem as vstage[d][s], stride VST

#define VST_ACC(accv, MTc, NTc) do {                                                   \
        int dl = wn + (NTc) * 16 + l16;                                                \
        int base = dl * VST + wm + (MTc) * 16 + quad * 4;                              \
        smem[base + 0] = f2bf(accv[0]); smem[base + 1] = f2bf(accv[1]);                \
        smem[base + 2] = f2bf(accv[2]); smem[base + 3] = f2bf(accv[3]);                \
    } while (0)

        VST_ACC(c00, 0, 0); VST_ACC(c01, 0, 1); VST_ACC(c02, 0, 2); VST_ACC(c03, 0, 3);
        VST_ACC(c10, 1, 0); VST_ACC(c11, 1, 1); VST_ACC(c12, 1, 2); VST_ACC(c13, 1, 3);
        VST_ACC(c20, 2, 0); VST_ACC(c21, 2, 1); VST_ACC(c22, 2, 2); VST_ACC(c23, 2, 3);
        VST_ACC(c30, 3, 0); VST_ACC(c31, 3, 1); VST_ACC(c32, 3, 2); VST_ACC(c33, 3, 3);
        __syncthreads();
        int dl = tid >> 1, sh = (tid & 1) * 64;
        int vcol = (n0 - 2048) + dl;          // 0..1023
        int h = vcol >> 6, dd = vcol & 63;
        int b = m0 >> 11, s0 = m0 & (S_LEN - 1);
        unsigned short* dst = vt + (((size_t)(b * NH + h) * DK + dd) * S_LEN + s0 + sh);
        const unsigned short* src = smem + dl * VST + sh;
#pragma unroll
        for (int i = 0; i < 64; i += 8)
            *(bf16x8*)&dst[i] = *(const bf16x8*)&src[i];
    }
}

// ---------------------------------------------------------------------------
// Out projection GEMM: C_fp32 = A_bf16 @ W_bf16^T.
// ---------------------------------------------------------------------------
__global__ __launch_bounds__(256) void gemm_out(const unsigned short* __restrict__ A,
                                                const unsigned short* __restrict__ W,
                                                float* __restrict__ C)
{
    __shared__ __align__(16) unsigned short As[128 * LDSP];
    __shared__ __align__(16) unsigned short Bs[128 * LDSP];
    const int tid  = threadIdx.x;
    const int wave = tid >> 6;
    const int lane = tid & 63;
    const int quad = lane >> 4;
    const int l16  = lane & 15;
    const int m0 = blockIdx.y * 128;
    const int n0 = blockIdx.x * 128;
    const int wm = (wave >> 1) * 64;
    const int wn = (wave & 1) * 64;

    GEMM_MAIN(A, W, 1024, 1024)

#define OUT_ST(accv, MTc, NTc) do {                                                    \
    int col = n0 + wn + (NTc) * 16 + l16;                                              \
    int rowb = m0 + wm + (MTc) * 16 + quad * 4;                                        \
    C[(size_t)(rowb + 0) * 1024 + col] = accv[0];                                      \
    C[(size_t)(rowb + 1) * 1024 + col] = accv[1];                                      \
    C[(size_t)(rowb + 2) * 1024 + col] = accv[2];                                      \
    C[(size_t)(rowb + 3) * 1024 + col] = accv[3];                                      \
} while (0)

    OUT_ST(c00, 0, 0); OUT_ST(c01, 0, 1); OUT_ST(c02, 0, 2); OUT_ST(c03, 0, 3);
    OUT_ST(c10, 1, 0); OUT_ST(c11, 1, 1); OUT_ST(c12, 1, 2); OUT_ST(c13, 1, 3);
    OUT_ST(c20, 2, 0); OUT_ST(c21, 2, 1); OUT_ST(c22, 2, 2); OUT_ST(c23, 2, 3);
    OUT_ST(c30, 3, 0); OUT_ST(c31, 3, 1); OUT_ST(c32, 3, 2); OUT_ST(c33, 3, 3);
}

// ---------------------------------------------------------------------------
// Flash attention, causal, soft-cap 50*tanh(s/50).
// Soft-cap bounds scores -> no online max / rescale (validated earlier).
// One wave = 16 q rows; 64-key chunks; per-wave P buffer in LDS.
//
// ROUND 0: causal load balance — block p handles qblk p AND 31-p (33 chunks).
// ROUND 1: XCD swizzle (kept: FETCH 260->99 MB) + K-reg prefetch (REVERTED:
//   +32 live VGPR under launch_bounds(256,4) forced a scratch spill —
//   VGPR_Count fell to 64 and WRITE_SIZE exploded 16->276 MB, dur +27%).
// ROUND 2: Round-0 loop body (no K prefetch, V hoisted over softmax) +
//   XCD swizzle + diagonal-only causal mask. K/V now come from a warm L2
//   (~200 cy) instead of thrashed L2/HBM (~500+ cy) — same Little's-law
//   gain as the failed prefetch, achieved by cutting latency instead of
//   raising in-flight bytes (which we can't afford in VGPRs).
// ---------------------------------------------------------------------------
#define PPL 72   // P-row stride in LDS (64 keys + 8 pad)

__global__ __launch_bounds__(256) void attn_fwd(const unsigned short* __restrict__ qr,
                                                const unsigned short* __restrict__ kr,
                                                const unsigned short* __restrict__ vt,
                                                unsigned short* __restrict__ aout)
{
    __shared__ __align__(16) unsigned short plds[4][16 * PPL];
    // XCD-aware swizzle: 1024 blocks, 8 XCDs, 128 blocks/XCD (bijective).
    // 8 bh per XCD -> 8 x 512 KB K/V = 4 MB = one XCD's L2.
    int bid  = blockIdx.x;
    int blk  = (bid & 7) * 128 + (bid >> 3);
    int pr   = blk & 15;
    int bh   = blk >> 4;
    int b    = bh >> 4, h = bh & 15;
    int wave = threadIdx.x >> 6;
    int lane = threadIdx.x & 63;
    int quad = lane >> 4, l16 = lane & 15;

    const unsigned short* kbase = kr + (size_t)bh * S_LEN * DK;
    const unsigned short* vbase = vt + (size_t)bh * DK * S_LEN;
    unsigned short* pw = &plds[wave][0];

// QK^T for one 64-key chunk: K loaded inline (consumed immediately; the
// only in-flight window we need is V-over-softmax below).
#define QK_CHUNK(j0_) do {                                                             \
    const unsigned short* kp = &kbase[(size_t)((j0_) + l16) * DK + quad * 8];          \
    bf16x8 ka = *(const bf16x8*)kp;                                                    \
    bf16x8 kb = *(const bf16x8*)(kp + 32);                                             \
    sc0 = MFMA(qf0, ka, sc0); sc0 = MFMA(qf1, kb, sc0);                                \
    ka = *(const bf16x8*)(kp + 16 * DK); kb = *(const bf16x8*)(kp + 16 * DK + 32);     \
    sc1 = MFMA(qf0, ka, sc1); sc1 = MFMA(qf1, kb, sc1);                                \
    ka = *(const bf16x8*)(kp + 32 * DK); kb = *(const bf16x8*)(kp + 32 * DK + 32);     \
    sc2 = MFMA(qf0, ka, sc2); sc2 = MFMA(qf1, kb, sc2);                                \
    ka = *(const bf16x8*)(kp + 48 * DK); kb = *(const bf16x8*)(kp + 48 * DK + 32);     \
    sc3 = MFMA(qf0, ka, sc3); sc3 = MFMA(qf1, kb, sc3);                                \
} while (0)

#define VLOAD_DECL(j0_)                                                                \
    const unsigned short* vp = vbase + (size_t)l16 * S_LEN + (j0_) + quad * 8;         \
    bf16x8 v00 = *(const bf16x8*)(vp);                                                 \
    bf16x8 v01 = *(const bf16x8*)(vp + 32);                                            \
    bf16x8 v10 = *(const bf16x8*)(vp + 16 * S_LEN);                                    \
    bf16x8 v11 = *(const bf16x8*)(vp + 16 * S_LEN + 32);                               \
    bf16x8 v20 = *(const bf16x8*)(vp + 32 * S_LEN);                                    \
    bf16x8 v21 = *(const bf16x8*)(vp + 32 * S_LEN + 32);                               \
    bf16x8 v30 = *(const bf16x8*)(vp + 48 * S_LEN);                                    \
    bf16x8 v31 = *(const bf16x8*)(vp + 48 * S_LEN + 32);

// unmasked softmax row update (non-diagonal chunks)
#define ROW_UPD_N(rc) do {                                                             \
    float p0 = cap_exp(sc0[rc]);                                                       \
    float p1 = cap_exp(sc1[rc]);                                                       \
    float p2 = cap_exp(sc2[rc]);                                                       \
    float p3 = cap_exp(sc3[rc]);                                                       \
    l##rc += (p0 + p1) + (p2 + p3);                                                    \
    int rb = (quad * 4 + (rc)) * PPL + l16;                                            \
    pw[rb]      = f2bf(p0);                                                            \
    pw[rb + 16] = f2bf(p1);                                                            \
    pw[rb + 32] = f2bf(p2);                                                            \
    pw[rb + 48] = f2bf(p3);                                                            \
} while (0)

// masked softmax row update (diagonal chunk only)
#define ROW_UPD_M(rc) do {                                                             \
    int qrow = q0w + quad * 4 + (rc);                                                  \
    float p0 = (j0 + l16      > qrow) ? 0.f : cap_exp(sc0[rc]);                        \
    float p1 = (j0 + 16 + l16 > qrow) ? 0.f : cap_exp(sc1[rc]);                        \
    float p2 = (j0 + 32 + l16 > qrow) ? 0.f : cap_exp(sc2[rc]);                        \
    float p3 = (j0 + 48 + l16 > qrow) ? 0.f : cap_exp(sc3[rc]);                        \
    l##rc += (p0 + p1) + (p2 + p3);                                                    \
    int rb = (quad * 4 + (rc)) * PPL + l16;                                            \
    pw[rb]      = f2bf(p0);                                                            \
    pw[rb + 16] = f2bf(p1);                                                            \
    pw[rb + 32] = f2bf(p2);                                                            \
    pw[rb + 48] = f2bf(p3);                                                            \
} while (0)

#define PV_MFMA() do {                                                                 \
    bf16x8 pf0 = *(const bf16x8*)&pw[l16 * PPL + quad * 8];                            \
    bf16x8 pf1 = *(const bf16x8*)&pw[l16 * PPL + 32 + quad * 8];                       \
    o0 = MFMA(pf0, v00, o0); o0 = MFMA(pf1, v01, o0);                                  \
    o1 = MFMA(pf0, v10, o1); o1 = MFMA(pf1, v11, o1);                                  \
    o2 = MFMA(pf0, v20, o2); o2 = MFMA(pf1, v21, o2);                                  \
    o3 = MFMA(pf0, v30, o3); o3 = MFMA(pf1, v31, o3);                                  \
} while (0)

    for (int side = 0; side < 2; ++side) {
        const int qblk = side ? (31 - pr) : pr;   // pairs sum to 33 chunks
        const int q0w  = qblk * 64 + wave * 16;

        const unsigned short* qbase = qr + ((size_t)bh * S_LEN + q0w) * DK;
        bf16x8 qf0 = *(const bf16x8*)&qbase[l16 * DK + quad * 8];
        bf16x8 qf1 = *(const bf16x8*)&qbase[l16 * DK + 32 + quad * 8];

        f32x4 zz = {0.f, 0.f, 0.f, 0.f};
        f32x4 o0 = zz, o1 = zz, o2 = zz, o3 = zz;
        float l0 = 0.f, l1 = 0.f, l2 = 0.f, l3 = 0.f;

        const int nch = qblk + 1;   // 64-key chunks; uniform across the block

        // ---- unmasked chunks 0 .. nch-2 ----
        for (int c = 0; c < nch - 1; ++c) {
            const int j0 = c * 64;
            f32x4 sc0 = zz, sc1 = zz, sc2 = zz, sc3 = zz;
            QK_CHUNK(j0);
            // V issued here: its vmcnt wait overlaps the softmax VALU below
            VLOAD_DECL(j0);
            ROW_UPD_N(0); ROW_UPD_N(1); ROW_UPD_N(2); ROW_UPD_N(3);
            asm volatile("s_waitcnt lgkmcnt(0)" ::: "memory");
            PV_MFMA();
        }

        // ---- diagonal chunk (c = nch-1): only place causal compares run ----
        {
            const int j0 = (nch - 1) * 64;
            f32x4 sc0 = zz, sc1 = zz, sc2 = zz, sc3 = zz;
            QK_CHUNK(j0);
            VLOAD_DECL(j0);
            ROW_UPD_M(0); ROW_UPD_M(1); ROW_UPD_M(2); ROW_UPD_M(3);
            asm volatile("s_waitcnt lgkmcnt(0)" ::: "memory");
            PV_MFMA();
        }

        // ---- deferred l reduction (16 lanes within quad) + output ----
#define OUT_ROW(rc) do {                                                               \
        float lr = l##rc;                                                              \
        lr += __shfl_xor(lr, 1); lr += __shfl_xor(lr, 2);                              \
        lr += __shfl_xor(lr, 4); lr += __shfl_xor(lr, 8);                              \
        int qrow = q0w + quad * 4 + (rc);                                              \
        size_t off = (size_t)(b * S_LEN + qrow) * DM + h * DK + l16;                   \
        float rl = 1.0f / lr;                                                          \
        aout[off +  0] = f2bf(o0[rc] * rl);                                            \
        aout[off + 16] = f2bf(o1[rc] * rl);                                            \
        aout[off + 32] = f2bf(o2[rc] * rl);                                            \
        aout[off + 48] = f2bf(o3[rc] * rl);                                            \
} while (0)

        OUT_ROW(0); OUT_ROW(1); OUT_ROW(2); OUT_ROW(3);
#undef OUT_ROW
    }
}

// ---------------------------------------------------------------------------
extern "C" void kernel_launch(void* const* d_in, const int* in_sizes, int n_in,
                              void* d_out, int out_size, void* d_ws, size_t ws_size,
                              hipStream_t stream)
{
    // identify inputs by element count (robust to ordering)
    const void* x = nullptr; const void* wqkv = nullptr; const void* wout = nullptr;
    for (int i = 0; i < n_in; ++i) {
        if      (in_sizes[i] == 8388608) x    = d_in[i];   // [4,2048,1024]
        else if (in_sizes[i] == 3145728) wqkv = d_in[i];   // [3072,1024]
        else if (in_sizes[i] == 1048576) wout = d_in[i];   // [1024,1024]
    }
    float* out = (float*)d_out;                      // [4,2048,1024] fp32
    unsigned short* ws   = (unsigned short*)d_ws;
    unsigned short* ob16 = (unsigned short*)d_out;   // d_out viewed as bf16 scratch

    // ws (48 MiB + 4 B): qr | kr | aout slots of 8,388,608 bf16 elems each.
    unsigned short* qr     = ws;
    unsigned short* kr     = ws + (size_t)8388608;
    unsigned short* aout   = ws + (size_t)16777216;
    int* flag              = (int*)(ws + (size_t)25165824);
    unsigned short* wqkvbf = aout;   // staged in aout slot; dead before attn writes
    unsigned short* woutbf = qr;     // staged in qr slot AFTER attn (qr then dead)

    // d_out bf16 view: vt [0, 8.4M) | xbf [8.4M, 16.8M); both dead before
    // gemm_out overwrites d_out with fp32 results.
    unsigned short* vt  = ob16;
    unsigned short* xbf = ob16 + (size_t)8388608;

    // 0) input dtype autodetect (bf16 expected; fp32 tolerated)
    detect_f32<<<1, 256, 0, stream>>>((const unsigned short*)x, flag);
    // 1) normalize x and w_qkv to bf16
    norm_bf16<<<4096, 256, 0, stream>>>(x, xbf, 8388608, flag);
    norm_bf16<<<1536, 256, 0, stream>>>(wqkv, wqkvbf, 3145728, flag);
    // 2) fused: qkv GEMM + RoPE(q,k) -> qr/kr [b,h,s,d] (q/8), v -> vt [b,h,d,s]
    gemm_fused<<<dim3(24, 64), 256, 0, stream>>>(xbf, wqkvbf, qr, kr, vt);
    // 3) causal soft-capped flash attention (balanced + XCD-local, no prefetch)
    attn_fwd<<<1024, 256, 0, stream>>>(qr, kr, vt, aout);
    // 4) normalize w_out into the now-dead qr slot
    norm_bf16<<<512, 256, 0, stream>>>(wout, woutbf, 1048576, flag);
    // 5) out_fp32 = aout @ w_out^T  (M=8192, N=1024, K=1024)
    gemm_out<<<dim3(8, 64), 256, 0, stream>>>(aout, woutbf, out);
}

// Round 4
// 386.861 us; speedup vs baseline: 1.4660x; 1.4222x over previous
//
#include <hip/hip_runtime.h>
#include <stdint.h>

#define S_LEN 2048
#define NH    16
#define DK    64
#define DM    1024

typedef __attribute__((ext_vector_type(8))) __bf16 bf16x8;
typedef __attribute__((ext_vector_type(8))) unsigned short u16x8;
typedef __attribute__((ext_vector_type(4))) float  f32x4;

static __device__ __forceinline__ unsigned short f2bf(float f) {
    union { float f; unsigned int u; } v; v.f = f;
    unsigned int r = v.u + 0x7FFFu + ((v.u >> 16) & 1u);
    return (unsigned short)(r >> 16);
}

// exp(50*tanh(s/50)) without libcalls: u=2^(2s/50/ln2)=e^(2s/50); tanh=1-2/(u+1)
static __device__ __forceinline__ float cap_exp(float s) {
    float u = exp2f(s * 0.0577078016f);              // e^(2s/50)
    float t = 1.0f - 2.0f * __builtin_amdgcn_rcpf(u + 1.0f);   // tanh(s/50)
    return exp2f(t * 72.1347520444f);                // e^(50*tanh)
}

// ---------------------------------------------------------------------------
// Input dtype detector (fp32 low-halves have wild bf16 exponents).
// ---------------------------------------------------------------------------
__global__ void detect_f32(const unsigned short* __restrict__ x, int* __restrict__ flag)
{
    __shared__ int tot;
    if (threadIdx.x == 0) tot = 0;
    __syncthreads();
    int weird = 0;
    for (int i = threadIdx.x; i < 16384; i += 256) {
        int e = (x[i] >> 7) & 0xFF;
        if (e == 0 || e < 87 || e > 167) weird++;
    }
    atomicAdd(&tot, weird);
    __syncthreads();
    if (threadIdx.x == 0) *flag = (tot > 4000) ? 1 : 0;
}

// ---------------------------------------------------------------------------
// Normalize an input buffer to bf16 (copy if bf16, convert if fp32).
// ---------------------------------------------------------------------------
__global__ __launch_bounds__(256) void norm_bf16(const void* __restrict__ src,
                                                 unsigned short* __restrict__ dst,
                                                 int n, const int* __restrict__ flag)
{
    const int isf32 = *flag;
    int i = (blockIdx.x * 256 + threadIdx.x) * 8;
    if (i >= n) return;
    if (isf32) {
        const float* p = (const float*)src + i;
        u16x8 o;
        o[0] = f2bf(p[0]); o[1] = f2bf(p[1]); o[2] = f2bf(p[2]); o[3] = f2bf(p[3]);
        o[4] = f2bf(p[4]); o[5] = f2bf(p[5]); o[6] = f2bf(p[6]); o[7] = f2bf(p[7]);
        *(u16x8*)&dst[i] = o;
    } else {
        *(uint4*)&dst[i] = *(const uint4*)((const unsigned short*)src + i);
    }
}

#define LDSP 40   // padded K-stride for A/B staging (32 + 8)
#define VST  136  // padded s-stride for V transpose staging (128 + 8)

#define MFMA(a, b, c) __builtin_amdgcn_mfma_f32_16x16x32_bf16((a), (b), (c), 0, 0, 0)

// Shared GEMM mainloop: named accumulators — no local arrays (scratch-spill fix).
#define GEMM_MAIN(Aptr, Wptr, lda_, ldw_)                                              \
    f32x4 zz = {0.f, 0.f, 0.f, 0.f};                                                   \
    f32x4 c00=zz,c01=zz,c02=zz,c03=zz, c10=zz,c11=zz,c12=zz,c13=zz,                    \
          c20=zz,c21=zz,c22=zz,c23=zz, c30=zz,c31=zz,c32=zz,c33=zz;                    \
    for (int k0 = 0; k0 < 1024; k0 += 32) {                                            \
        __syncthreads();                                                               \
        {                                                                              \
            int row = tid >> 2, col = (tid & 3) << 3;                                  \
            *(bf16x8*)&As[row * LDSP + col] =                                          \
                *(const bf16x8*)&Aptr[(size_t)(m0 + row) * (lda_) + k0 + col];         \
            *(bf16x8*)&Bs[row * LDSP + col] =                                          \
                *(const bf16x8*)&Wptr[(size_t)(n0 + row) * (ldw_) + k0 + col];         \
            row += 64;                                                                 \
            *(bf16x8*)&As[row * LDSP + col] =                                          \
                *(const bf16x8*)&Aptr[(size_t)(m0 + row) * (lda_) + k0 + col];         \
            *(bf16x8*)&Bs[row * LDSP + col] =                                          \
                *(const bf16x8*)&Wptr[(size_t)(n0 + row) * (ldw_) + k0 + col];         \
        }                                                                              \
        __syncthreads();                                                               \
        bf16x8 a0 = *(const bf16x8*)&As[(wm +  0 + l16) * LDSP + quad * 8];            \
        bf16x8 a1 = *(const bf16x8*)&As[(wm + 16 + l16) * LDSP + quad * 8];            \
        bf16x8 a2 = *(const bf16x8*)&As[(wm + 32 + l16) * LDSP + quad * 8];            \
        bf16x8 a3 = *(const bf16x8*)&As[(wm + 48 + l16) * LDSP + quad * 8];            \
        bf16x8 b0 = *(const bf16x8*)&Bs[(wn +  0 + l16) * LDSP + quad * 8];            \
        bf16x8 b1 = *(const bf16x8*)&Bs[(wn + 16 + l16) * LDSP + quad * 8];            \
        bf16x8 b2 = *(const bf16x8*)&Bs[(wn + 32 + l16) * LDSP + quad * 8];            \
        bf16x8 b3 = *(const bf16x8*)&Bs[(wn + 48 + l16) * LDSP + quad * 8];            \
        c00 = MFMA(a0, b0, c00); c01 = MFMA(a0, b1, c01);                              \
        c02 = MFMA(a0, b2, c02); c03 = MFMA(a0, b3, c03);                              \
        c10 = MFMA(a1, b0, c10); c11 = MFMA(a1, b1, c11);                              \
        c12 = MFMA(a1, b2, c12); c13 = MFMA(a1, b3, c13);                              \
        c20 = MFMA(a2, b0, c20); c21 = MFMA(a2, b1, c21);                              \
        c22 = MFMA(a2, b2, c22); c23 = MFMA(a2, b3, c23);                              \
        c30 = MFMA(a3, b0, c30); c31 = MFMA(a3, b1, c31);                              \
        c32 = MFMA(a3, b2, c32); c33 = MFMA(a3, b3, c33);                              \
    }

// ---------------------------------------------------------------------------
// Fused QKV GEMM + RoPE/V-transpose epilogue.
// ---------------------------------------------------------------------------
__global__ __launch_bounds__(256) void gemm_fused(const unsigned short* __restrict__ A,
                                                  const unsigned short* __restrict__ W,
                                                  unsigned short* __restrict__ qr,
                                                  unsigned short* __restrict__ kr,
                                                  unsigned short* __restrict__ vt)
{
    __shared__ __align__(16) unsigned short smem[128 * VST]; // As/Bs union V-stage
    unsigned short* As = smem;
    unsigned short* Bs = smem + 128 * LDSP;

    const int tid  = threadIdx.x;
    const int wave = tid >> 6;
    const int lane = tid & 63;
    const int quad = lane >> 4;
    const int l16  = lane & 15;
    const int m0 = blockIdx.y * 128;
    const int n0 = blockIdx.x * 128;
    const int wm = (wave >> 1) * 64;
    const int wn = (wave & 1) * 64;

    GEMM_MAIN(A, W, 1024, 1024)

    const int cls = n0 >> 10;   // 0=Q, 1=K, 2=V  (block-uniform)
    if (cls < 2) {
        unsigned short* dst = cls ? kr : qr;
        const float qs = cls ? 1.0f : 0.125f;   // fold 1/sqrt(64) into q

#define ROPE_R(accv, MTc, rc, invf_, even_, h_, d_) do {                               \
        int row = m0 + wm + (MTc) * 16 + quad * 4 + (rc);                              \
        int s = row & (S_LEN - 1), b = row >> 11;                                      \
        float sn, cs;                                                                  \
        sincosf((float)s * (invf_), &sn, &cs);                                         \
        float own = accv[rc];                                                          \
        float oth = __shfl_xor(own, 1);                                                \
        float res = (even_) ? (own * cs - oth * sn) : (oth * sn + own * cs);           \
        dst[((size_t)(b * NH + (h_)) * S_LEN + s) * DK + (d_)] = f2bf(res * qs);       \
    } while (0)

#define ROPE_ST(accv, MTc, NTc) do {                                                   \
        int col = (n0 & 1023) + wn + (NTc) * 16 + l16;                                 \
        int h = col >> 6, d = col & 63;                                                \
        float invf = exp2f(-(float)(d >> 1) * 0.41524101186f);                         \
        int even = !(d & 1);                                                           \
        ROPE_R(accv, MTc, 0, invf, even, h, d);                                        \
        ROPE_R(accv, MTc, 1, invf, even, h, d);                                        \
        ROPE_R(accv, MTc, 2, invf, even, h, d);                                        \
        ROPE_R(accv, MTc, 3, invf, even, h, d);                                        \
    } while (0)

        ROPE_ST(c00, 0, 0); ROPE_ST(c01, 0, 1); ROPE_ST(c02, 0, 2); ROPE_ST(c03, 0, 3);
        ROPE_ST(c10, 1, 0); ROPE_ST(c11, 1, 1); ROPE_ST(c12, 1, 2); ROPE_ST(c13, 1, 3);
        ROPE_ST(c20, 2, 0); ROPE_ST(c21, 2, 1); ROPE_ST(c22, 2, 2); ROPE_ST(c23, 2, 3);
        ROPE_ST(c30, 3, 0); ROPE_ST(c31, 3, 1); ROPE_ST(c32, 3, 2); ROPE_ST(c33, 3, 3);
    } else {
        __syncthreads();   // As/Bs done; reuse smem as vstage[d][s], stride VST

#define VST_ACC(accv, MTc, NTc) do {                                                   \
        int dl = wn + (NTc) * 16 + l16;                                                \
        int base = dl * VST + wm + (MTc) * 16 + quad * 4;                              \
        smem[base + 0] = f2bf(accv[0]); smem[base + 1] = f2bf(accv[1]);                \
        smem[base + 2] = f2bf(accv[2]); smem[base + 3] = f2bf(accv[3]);                \
    } while (0)

        VST_ACC(c00, 0, 0); VST_ACC(c01, 0, 1); VST_ACC(c02, 0, 2); VST_ACC(c03, 0, 3);
        VST_ACC(c10, 1, 0); VST_ACC(c11, 1, 1); VST_ACC(c12, 1, 2); VST_ACC(c13, 1, 3);
        VST_ACC(c20, 2, 0); VST_ACC(c21, 2, 1); VST_ACC(c22, 2, 2); VST_ACC(c23, 2, 3);
        VST_ACC(c30, 3, 0); VST_ACC(c31, 3, 1); VST_ACC(c32, 3, 2); VST_ACC(c33, 3, 3);
        __syncthreads();
        int dl = tid >> 1, sh = (tid & 1) * 64;
        int vcol = (n0 - 2048) + dl;          // 0..1023
        int h = vcol >> 6, dd = vcol & 63;
        int b = m0 >> 11, s0 = m0 & (S_LEN - 1);
        unsigned short* dst = vt + (((size_t)(b * NH + h) * DK + dd) * S_LEN + s0 + sh);
        const unsigned short* src = smem + dl * VST + sh;
#pragma unroll
        for (int i = 0; i < 64; i += 8)
            *(bf16x8*)&dst[i] = *(const bf16x8*)&src[i];
    }
}

// ---------------------------------------------------------------------------
// Out projection GEMM: C_fp32 = A_bf16 @ W_bf16^T.
// ---------------------------------------------------------------------------
__global__ __launch_bounds__(256) void gemm_out(const unsigned short* __restrict__ A,
                                                const unsigned short* __restrict__ W,
                                                float* __restrict__ C)
{
    __shared__ __align__(16) unsigned short As[128 * LDSP];
    __shared__ __align__(16) unsigned short Bs[128 * LDSP];
    const int tid  = threadIdx.x;
    const int wave = tid >> 6;
    const int lane = tid & 63;
    const int quad = lane >> 4;
    const int l16  = lane & 15;
    const int m0 = blockIdx.y * 128;
    const int n0 = blockIdx.x * 128;
    const int wm = (wave >> 1) * 64;
    const int wn = (wave & 1) * 64;

    GEMM_MAIN(A, W, 1024, 1024)

#define OUT_ST(accv, MTc, NTc) do {                                                    \
    int col = n0 + wn + (NTc) * 16 + l16;                                              \
    int rowb = m0 + wm + (MTc) * 16 + quad * 4;                                        \
    C[(size_t)(rowb + 0) * 1024 + col] = accv[0];                                      \
    C[(size_t)(rowb + 1) * 1024 + col] = accv[1];                                      \
    C[(size_t)(rowb + 2) * 1024 + col] = accv[2];                                      \
    C[(size_t)(rowb + 3) * 1024 + col] = accv[3];                                      \
} while (0)

    OUT_ST(c00, 0, 0); OUT_ST(c01, 0, 1); OUT_ST(c02, 0, 2); OUT_ST(c03, 0, 3);
    OUT_ST(c10, 1, 0); OUT_ST(c11, 1, 1); OUT_ST(c12, 1, 2); OUT_ST(c13, 1, 3);
    OUT_ST(c20, 2, 0); OUT_ST(c21, 2, 1); OUT_ST(c22, 2, 2); OUT_ST(c23, 2, 3);
    OUT_ST(c30, 3, 0); OUT_ST(c31, 3, 1); OUT_ST(c32, 3, 2); OUT_ST(c33, 3, 3);
}

// ---------------------------------------------------------------------------
// Flash attention, causal, soft-cap 50*tanh(s/50).
// Soft-cap bounds scores -> no online max / rescale (validated earlier).
// One wave = 16 q rows; 64-key chunks; per-wave P buffer in LDS.
//
// ROUND 0: causal load balance — block p handles qblk p AND 31-p (33 chunks).
// ROUND 1: XCD swizzle + K-reg prefetch: prefetch spilled (REVERTED).
// ROUND 2: swizzle alone: FETCH 260->25 MB but dur 259->312 — L2 hotspot
//   contention from 128 lockstep blocks per XCD. Swizzle REVERTED.
// ROUND 3: block-level cooperative K/V staging (the structural fix): all 4
//   waves previously issued IDENTICAL K/V global loads (4x redundant) with
//   <=512B in flight each -> latency-bound at 32% VALUBusy. Now the block
//   stages the 16KB chunk ONCE via global_load_lds (width 16), double-
//   buffered: stage chunk c+1 while computing chunk c from LDS. Fragment
//   reads XOR-swizzled (col ^= row&7); inverse swizzle applied on the
//   per-lane GLOBAL source (gll dest must stay linear — guide rule #21).
//   LDS 41KB -> 3 blocks/CU.
// ---------------------------------------------------------------------------
#define PPL 72   // P-row stride in LDS (64 keys + 8 pad)

__global__ __launch_bounds__(256) void attn_fwd(const unsigned short* __restrict__ qr,
                                                const unsigned short* __restrict__ kr,
                                                const unsigned short* __restrict__ vt,
                                                unsigned short* __restrict__ aout)
{
    __shared__ __align__(16) unsigned short kvs[2][2][4096]; // [buf][K|V][64x64]
    __shared__ __align__(16) unsigned short plds[4][16 * PPL];
    int blk  = blockIdx.x;                // 32 bh x 16 pair-ids = 1024
    int pr   = blk & 15;
    int bh   = blk >> 4;
    int b    = bh >> 4, h = bh & 15;
    int wave = threadIdx.x >> 6;
    int lane = threadIdx.x & 63;
    int quad = lane >> 4, l16 = lane & 15;

    const unsigned short* kbase = kr + (size_t)bh * S_LEN * DK;
    const unsigned short* vbase = vt + (size_t)bh * DK * S_LEN;
    unsigned short* pw = &plds[wave][0];

    // ---- staging geometry (per-thread constants) ----
    // lds linear elem offset o = r*2048 + wave*512 + lane*8 (HW adds lane*16B)
    // row = o/64 = r*32 + wave*8 + (lane>>3); col16 = lane&7
    // stored content is col-swizzled: LDS[row][c] = G[row][c ^ (row&7)]
    const int lam3  = lane >> 3;                 // == row & 7
    const int sc3p  = (lane & 7) ^ lam3;         // source col for this lane
    const int strow = wave * 8 + lam3;           // row for r=0 (r=1: +32)
    const int stcol = sc3p * 8;                  // elem offset within row
    // fragment read offset: row=l16+16t, want col=quad -> read col quad^(row&7)
    const int kfA = l16 * 64 + ((quad ^ (l16 & 7)) << 3);

#define STAGE(c_, nb_) do {                                                            \
    const int j0s = (c_) * 64;                                                         \
    unsigned short* kd = &kvs[nb_][0][wave * 512];                                     \
    unsigned short* vd = &kvs[nb_][1][wave * 512];                                     \
    const unsigned short* kg = kbase + (size_t)(j0s + strow) * 64 + stcol;             \
    const unsigned short* vg = vbase + (size_t)strow * S_LEN + j0s + stcol;            \
    __builtin_amdgcn_global_load_lds(                                                  \
        (const __attribute__((address_space(1))) unsigned int*)kg,                     \
        (__attribute__((address_space(3))) unsigned int*)kd, 16, 0, 0);                \
    __builtin_amdgcn_global_load_lds(                                                  \
        (const __attribute__((address_space(1))) unsigned int*)(kg + 32 * 64),         \
        (__attribute__((address_space(3))) unsigned int*)(kd + 2048), 16, 0, 0);       \
    __builtin_amdgcn_global_load_lds(                                                  \
        (const __attribute__((address_space(1))) unsigned int*)vg,                     \
        (__attribute__((address_space(3))) unsigned int*)vd, 16, 0, 0);                \
    __builtin_amdgcn_global_load_lds(                                                  \
        (const __attribute__((address_space(1))) unsigned int*)(vg + 32 * S_LEN),      \
        (__attribute__((address_space(3))) unsigned int*)(vd + 2048), 16, 0, 0);       \
} while (0)

#define QK_LDS(kb_) do {                                                               \
    bf16x8 ka, kb;                                                                     \
    ka = *(const bf16x8*)&(kb_)[kfA];          kb = *(const bf16x8*)&(kb_)[kfA ^ 32];  \
    sc0 = MFMA(qf0, ka, sc0); sc0 = MFMA(qf1, kb, sc0);                                \
    ka = *(const bf16x8*)&(kb_)[kfA + 1024];   kb = *(const bf16x8*)&(kb_)[(kfA + 1024) ^ 32]; \
    sc1 = MFMA(qf0, ka, sc1); sc1 = MFMA(qf1, kb, sc1);                                \
    ka = *(const bf16x8*)&(kb_)[kfA + 2048];   kb = *(const bf16x8*)&(kb_)[(kfA + 2048) ^ 32]; \
    sc2 = MFMA(qf0, ka, sc2); sc2 = MFMA(qf1, kb, sc2);                                \
    ka = *(const bf16x8*)&(kb_)[kfA + 3072];   kb = *(const bf16x8*)&(kb_)[(kfA + 3072) ^ 32]; \
    sc3 = MFMA(qf0, ka, sc3); sc3 = MFMA(qf1, kb, sc3);                                \
} while (0)

#define PV_LDS(vb_) do {                                                               \
    bf16x8 pf0 = *(const bf16x8*)&pw[l16 * PPL + quad * 8];                            \
    bf16x8 pf1 = *(const bf16x8*)&pw[l16 * PPL + 32 + quad * 8];                       \
    bf16x8 va, vb;                                                                     \
    va = *(const bf16x8*)&(vb_)[kfA];          vb = *(const bf16x8*)&(vb_)[kfA ^ 32];  \
    o0 = MFMA(pf0, va, o0); o0 = MFMA(pf1, vb, o0);                                    \
    va = *(const bf16x8*)&(vb_)[kfA + 1024];   vb = *(const bf16x8*)&(vb_)[(kfA + 1024) ^ 32]; \
    o1 = MFMA(pf0, va, o1); o1 = MFMA(pf1, vb, o1);                                    \
    va = *(const bf16x8*)&(vb_)[kfA + 2048];   vb = *(const bf16x8*)&(vb_)[(kfA + 2048) ^ 32]; \
    o2 = MFMA(pf0, va, o2); o2 = MFMA(pf1, vb, o2);                                    \
    va = *(const bf16x8*)&(vb_)[kfA + 3072];   vb = *(const bf16x8*)&(vb_)[(kfA + 3072) ^ 32]; \
    o3 = MFMA(pf0, va, o3); o3 = MFMA(pf1, vb, o3);                                    \
} while (0)

// unmasked softmax row update (non-diagonal chunks)
#define ROW_UPD_N(rc) do {                                                             \
    float p0 = cap_exp(sc0[rc]);                                                       \
    float p1 = cap_exp(sc1[rc]);                                                       \
    float p2 = cap_exp(sc2[rc]);                                                       \
    float p3 = cap_exp(sc3[rc]);                                                       \
    l##rc += (p0 + p1) + (p2 + p3);                                                    \
    int rb = (quad * 4 + (rc)) * PPL + l16;                                            \
    pw[rb]      = f2bf(p0);                                                            \
    pw[rb + 16] = f2bf(p1);                                                            \
    pw[rb + 32] = f2bf(p2);                                                            \
    pw[rb + 48] = f2bf(p3);                                                            \
} while (0)

// masked softmax row update (diagonal chunk only)
#define ROW_UPD_M(rc) do {                                                             \
    int qrow = q0w + quad * 4 + (rc);                                                  \
    float p0 = (j0 + l16      > qrow) ? 0.f : cap_exp(sc0[rc]);                        \
    float p1 = (j0 + 16 + l16 > qrow) ? 0.f : cap_exp(sc1[rc]);                        \
    float p2 = (j0 + 32 + l16 > qrow) ? 0.f : cap_exp(sc2[rc]);                        \
    float p3 = (j0 + 48 + l16 > qrow) ? 0.f : cap_exp(sc3[rc]);                        \
    l##rc += (p0 + p1) + (p2 + p3);                                                    \
    int rb = (quad * 4 + (rc)) * PPL + l16;                                            \
    pw[rb]      = f2bf(p0);                                                            \
    pw[rb + 16] = f2bf(p1);                                                            \
    pw[rb + 32] = f2bf(p2);                                                            \
    pw[rb + 48] = f2bf(p3);                                                            \
} while (0)

    for (int side = 0; side < 2; ++side) {
        const int qblk = side ? (31 - pr) : pr;   // pairs sum to 33 chunks
        const int q0w  = qblk * 64 + wave * 16;

        const unsigned short* qbase = qr + ((size_t)bh * S_LEN + q0w) * DK;
        bf16x8 qf0 = *(const bf16x8*)&qbase[l16 * DK + quad * 8];
        bf16x8 qf1 = *(const bf16x8*)&qbase[l16 * DK + 32 + quad * 8];

        f32x4 zz = {0.f, 0.f, 0.f, 0.f};
        f32x4 o0 = zz, o1 = zz, o2 = zz, o3 = zz;
        float l0 = 0.f, l1 = 0.f, l2 = 0.f, l3 = 0.f;

        const int nch = qblk + 1;   // 64-key chunks; uniform across the block

        // prologue: stage chunk 0 into buf 0
        STAGE(0, 0);
        asm volatile("s_waitcnt vmcnt(0)" ::: "memory");
        __syncthreads();
        int cb = 0;

        // ---- unmasked chunks 0 .. nch-2 (stage c+1 while computing c) ----
        for (int c = 0; c < nch - 1; ++c) {
            STAGE(c + 1, cb ^ 1);
            f32x4 sc0 = zz, sc1 = zz, sc2 = zz, sc3 = zz;
            QK_LDS(&kvs[cb][0][0]);
            ROW_UPD_N(0); ROW_UPD_N(1); ROW_UPD_N(2); ROW_UPD_N(3);
            // intra-wave LDS write->read ordering (per-wave P buffer)
            asm volatile("s_waitcnt lgkmcnt(0)" ::: "memory");
            PV_LDS(&kvs[cb][1][0]);
            asm volatile("s_waitcnt vmcnt(0)" ::: "memory");
            __syncthreads();
            cb ^= 1;
        }

        // ---- diagonal chunk (c = nch-1): only place causal compares run ----
        {
            const int j0 = (nch - 1) * 64;
            f32x4 sc0 = zz, sc1 = zz, sc2 = zz, sc3 = zz;
            QK_LDS(&kvs[cb][0][0]);
            ROW_UPD_M(0); ROW_UPD_M(1); ROW_UPD_M(2); ROW_UPD_M(3);
            asm volatile("s_waitcnt lgkmcnt(0)" ::: "memory");
            PV_LDS(&kvs[cb][1][0]);
            __syncthreads();   // protect bufs before next side's prologue
        }

        // ---- deferred l reduction (16 lanes within quad) + output ----
#define OUT_ROW(rc) do {                                                               \
        float lr = l##rc;                                                              \
        lr += __shfl_xor(lr, 1); lr += __shfl_xor(lr, 2);                              \
        lr += __shfl_xor(lr, 4); lr += __shfl_xor(lr, 8);                              \
        int qrow = q0w + quad * 4 + (rc);                                              \
        size_t off = (size_t)(b * S_LEN + qrow) * DM + h * DK + l16;                   \
        float rl = 1.0f / lr;                                                          \
        aout[off +  0] = f2bf(o0[rc] * rl);                                            \
        aout[off + 16] = f2bf(o1[rc] * rl);                                            \
        aout[off + 32] = f2bf(o2[rc] * rl);                                            \
        aout[off + 48] = f2bf(o3[rc] * rl);                                            \
} while (0)

        OUT_ROW(0); OUT_ROW(1); OUT_ROW(2); OUT_ROW(3);
#undef OUT_ROW
    }
}

// ---------------------------------------------------------------------------
extern "C" void kernel_launch(void* const* d_in, const int* in_sizes, int n_in,
                              void* d_out, int out_size, void* d_ws, size_t ws_size,
                              hipStream_t stream)
{
    // identify inputs by element count (robust to ordering)
    const void* x = nullptr; const void* wqkv = nullptr; const void* wout = nullptr;
    for (int i = 0; i < n_in; ++i) {
        if      (in_sizes[i] == 8388608) x    = d_in[i];   // [4,2048,1024]
        else if (in_sizes[i] == 3145728) wqkv = d_in[i];   // [3072,1024]
        else if (in_sizes[i] == 1048576) wout = d_in[i];   // [1024,1024]
    }
    float* out = (float*)d_out;                      // [4,2048,1024] fp32
    unsigned short* ws   = (unsigned short*)d_ws;
    unsigned short* ob16 = (unsigned short*)d_out;   // d_out viewed as bf16 scratch

    // ws (48 MiB + 4 B): qr | kr | aout slots of 8,388,608 bf16 elems each.
    unsigned short* qr     = ws;
    unsigned short* kr     = ws + (size_t)8388608;
    unsigned short* aout   = ws + (size_t)16777216;
    int* flag              = (int*)(ws + (size_t)25165824);
    unsigned short* wqkvbf = aout;   // staged in aout slot; dead before attn writes
    unsigned short* woutbf = qr;     // staged in qr slot AFTER attn (qr then dead)

    // d_out bf16 view: vt [0, 8.4M) | xbf [8.4M, 16.8M); both dead before
    // gemm_out overwrites d_out with fp32 results.
    unsigned short* vt  = ob16;
    unsigned short* xbf = ob16 + (size_t)8388608;

    // 0) input dtype autodetect (bf16 expected; fp32 tolerated)
    detect_f32<<<1, 256, 0, stream>>>((const unsigned short*)x, flag);
    // 1) normalize x and w_qkv to bf16
    norm_bf16<<<4096, 256, 0, stream>>>(x, xbf, 8388608, flag);
    norm_bf16<<<1536, 256, 0, stream>>>(wqkv, wqkvbf, 3145728, flag);
    // 2) fused: qkv GEMM + RoPE(q,k) -> qr/kr [b,h,s,d] (q/8), v -> vt [b,h,d,s]
    gemm_fused<<<dim3(24, 64), 256, 0, stream>>>(xbf, wqkvbf, qr, kr, vt);
    // 3) causal soft-capped flash attention (balanced + LDS-staged K/V dbuf)
    attn_fwd<<<1024, 256, 0, stream>>>(qr, kr, vt, aout);
    // 4) normalize w_out into the now-dead qr slot
    norm_bf16<<<512, 256, 0, stream>>>(wout, woutbf, 1048576, flag);
    // 5) out_fp32 = aout @ w_out^T  (M=8192, N=1024, K=1024)
    gemm_out<<<dim3(8, 64), 256, 0, stream>>>(aout, woutbf, out);
}

// Round 5
// 382.991 us; speedup vs baseline: 1.4808x; 1.0101x over previous
//
#include <hip/hip_runtime.h>
#include <stdint.h>

#define S_LEN 2048
#define NH    16
#define DK    64
#define DM    1024

typedef __attribute__((ext_vector_type(8))) __bf16 bf16x8;
typedef __attribute__((ext_vector_type(8))) unsigned short u16x8;
typedef __attribute__((ext_vector_type(4))) float  f32x4;

static __device__ __forceinline__ unsigned short f2bf(float f) {
    union { float f; unsigned int u; } v; v.f = f;
    unsigned int r = v.u + 0x7FFFu + ((v.u >> 16) & 1u);
    return (unsigned short)(r >> 16);
}

// exp(50*tanh(s/50)) for PRE-SCALED s' = s*2/(50*ln2):
//   u = 2^s' = e^(2s/50);  w = 1/(u+1);  tanh = 1-2w
//   p = exp2(72.1347*(1-2w)) = exp2(fma(w, -144.2695, 72.1347))
// (the s*0.0577 mul is folded into the Q scale in gemm_fused)
static __device__ __forceinline__ float cap_exp2(float sp) {
    float u = exp2f(sp);
    float w = __builtin_amdgcn_rcpf(u + 1.0f);
    return exp2f(__builtin_fmaf(w, -144.2695040888f, 72.1347520444f));
}

// ---------------------------------------------------------------------------
// Input dtype detector (fp32 low-halves have wild bf16 exponents).
// ---------------------------------------------------------------------------
__global__ void detect_f32(const unsigned short* __restrict__ x, int* __restrict__ flag)
{
    __shared__ int tot;
    if (threadIdx.x == 0) tot = 0;
    __syncthreads();
    int weird = 0;
    for (int i = threadIdx.x; i < 16384; i += 256) {
        int e = (x[i] >> 7) & 0xFF;
        if (e == 0 || e < 87 || e > 167) weird++;
    }
    atomicAdd(&tot, weird);
    __syncthreads();
    if (threadIdx.x == 0) *flag = (tot > 4000) ? 1 : 0;
}

// ---------------------------------------------------------------------------
// Normalize an input buffer to bf16 (copy if bf16, convert if fp32).
// ---------------------------------------------------------------------------
__global__ __launch_bounds__(256) void norm_bf16(const void* __restrict__ src,
                                                 unsigned short* __restrict__ dst,
                                                 int n, const int* __restrict__ flag)
{
    const int isf32 = *flag;
    int i = (blockIdx.x * 256 + threadIdx.x) * 8;
    if (i >= n) return;
    if (isf32) {
        const float* p = (const float*)src + i;
        u16x8 o;
        o[0] = f2bf(p[0]); o[1] = f2bf(p[1]); o[2] = f2bf(p[2]); o[3] = f2bf(p[3]);
        o[4] = f2bf(p[4]); o[5] = f2bf(p[5]); o[6] = f2bf(p[6]); o[7] = f2bf(p[7]);
        *(u16x8*)&dst[i] = o;
    } else {
        *(uint4*)&dst[i] = *(const uint4*)((const unsigned short*)src + i);
    }
}

#define LDSP 40   // padded K-stride for A/B staging (32 + 8)
#define VST  136  // padded s-stride for V transpose staging (128 + 8)

#define MFMA(a, b, c) __builtin_amdgcn_mfma_f32_16x16x32_bf16((a), (b), (c), 0, 0, 0)

// Shared GEMM mainloop: named accumulators — no local arrays (scratch-spill fix).
#define GEMM_MAIN(Aptr, Wptr, lda_, ldw_)                                              \
    f32x4 zz = {0.f, 0.f, 0.f, 0.f};                                                   \
    f32x4 c00=zz,c01=zz,c02=zz,c03=zz, c10=zz,c11=zz,c12=zz,c13=zz,                    \
          c20=zz,c21=zz,c22=zz,c23=zz, c30=zz,c31=zz,c32=zz,c33=zz;                    \
    for (int k0 = 0; k0 < 1024; k0 += 32) {                                            \
        __syncthreads();                                                               \
        {                                                                              \
            int row = tid >> 2, col = (tid & 3) << 3;                                  \
            *(bf16x8*)&As[row * LDSP + col] =                                          \
                *(const bf16x8*)&Aptr[(size_t)(m0 + row) * (lda_) + k0 + col];         \
            *(bf16x8*)&Bs[row * LDSP + col] =                                          \
                *(const bf16x8*)&Wptr[(size_t)(n0 + row) * (ldw_) + k0 + col];         \
            row += 64;                                                                 \
            *(bf16x8*)&As[row * LDSP + col] =                                          \
                *(const bf16x8*)&Aptr[(size_t)(m0 + row) * (lda_) + k0 + col];         \
            *(bf16x8*)&Bs[row * LDSP + col] =                                          \
                *(const bf16x8*)&Wptr[(size_t)(n0 + row) * (ldw_) + k0 + col];         \
        }                                                                              \
        __syncthreads();                                                               \
        bf16x8 a0 = *(const bf16x8*)&As[(wm +  0 + l16) * LDSP + quad * 8];            \
        bf16x8 a1 = *(const bf16x8*)&As[(wm + 16 + l16) * LDSP + quad * 8];            \
        bf16x8 a2 = *(const bf16x8*)&As[(wm + 32 + l16) * LDSP + quad * 8];            \
        bf16x8 a3 = *(const bf16x8*)&As[(wm + 48 + l16) * LDSP + quad * 8];            \
        bf16x8 b0 = *(const bf16x8*)&Bs[(wn +  0 + l16) * LDSP + quad * 8];            \
        bf16x8 b1 = *(const bf16x8*)&Bs[(wn + 16 + l16) * LDSP + quad * 8];            \
        bf16x8 b2 = *(const bf16x8*)&Bs[(wn + 32 + l16) * LDSP + quad * 8];            \
        bf16x8 b3 = *(const bf16x8*)&Bs[(wn + 48 + l16) * LDSP + quad * 8];            \
        c00 = MFMA(a0, b0, c00); c01 = MFMA(a0, b1, c01);                              \
        c02 = MFMA(a0, b2, c02); c03 = MFMA(a0, b3, c03);                              \
        c10 = MFMA(a1, b0, c10); c11 = MFMA(a1, b1, c11);                              \
        c12 = MFMA(a1, b2, c12); c13 = MFMA(a1, b3, c13);                              \
        c20 = MFMA(a2, b0, c20); c21 = MFMA(a2, b1, c21);                              \
        c22 = MFMA(a2, b2, c22); c23 = MFMA(a2, b3, c23);                              \
        c30 = MFMA(a3, b0, c30); c31 = MFMA(a3, b1, c31);                              \
        c32 = MFMA(a3, b2, c32); c33 = MFMA(a3, b3, c33);                              \
    }

// ---------------------------------------------------------------------------
// Fused QKV GEMM + RoPE/V-transpose epilogue.
// ---------------------------------------------------------------------------
__global__ __launch_bounds__(256) void gemm_fused(const unsigned short* __restrict__ A,
                                                  const unsigned short* __restrict__ W,
                                                  unsigned short* __restrict__ qr,
                                                  unsigned short* __restrict__ kr,
                                                  unsigned short* __restrict__ vt)
{
    __shared__ __align__(16) unsigned short smem[128 * VST]; // As/Bs union V-stage
    unsigned short* As = smem;
    unsigned short* Bs = smem + 128 * LDSP;

    const int tid  = threadIdx.x;
    const int wave = tid >> 6;
    const int lane = tid & 63;
    const int quad = lane >> 4;
    const int l16  = lane & 15;
    const int m0 = blockIdx.y * 128;
    const int n0 = blockIdx.x * 128;
    const int wm = (wave >> 1) * 64;
    const int wn = (wave & 1) * 64;

    GEMM_MAIN(A, W, 1024, 1024)

    const int cls = n0 >> 10;   // 0=Q, 1=K, 2=V  (block-uniform)
    if (cls < 2) {
        unsigned short* dst = cls ? kr : qr;
        // Q scale folds 1/sqrt(64) AND the soft-cap exp pre-scale
        // 2/(50*ln2) = 0.0577078016: scores arrive ready for exp2.
        const float qs = cls ? 1.0f : 0.125f * 0.0577078016f;

#define ROPE_R(accv, MTc, rc, invf_, even_, h_, d_) do {                               \
        int row = m0 + wm + (MTc) * 16 + quad * 4 + (rc);                              \
        int s = row & (S_LEN - 1), b = row >> 11;                                      \
        float sn, cs;                                                                  \
        sincosf((float)s * (invf_), &sn, &cs);                                         \
        float own = accv[rc];                                                          \
        float oth = __shfl_xor(own, 1);                                                \
        float res = (even_) ? (own * cs - oth * sn) : (oth * sn + own * cs);           \
        dst[((size_t)(b * NH + (h_)) * S_LEN + s) * DK + (d_)] = f2bf(res * qs);       \
    } while (0)

#define ROPE_ST(accv, MTc, NTc) do {                                                   \
        int col = (n0 & 1023) + wn + (NTc) * 16 + l16;                                 \
        int h = col >> 6, d = col & 63;                                                \
        float invf = exp2f(-(float)(d >> 1) * 0.41524101186f);                         \
        int even = !(d & 1);                                                           \
        ROPE_R(accv, MTc, 0, invf, even, h, d);                                        \
        ROPE_R(accv, MTc, 1, invf, even, h, d);                                        \
        ROPE_R(accv, MTc, 2, invf, even, h, d);                                        \
        ROPE_R(accv, MTc, 3, invf, even, h, d);                                        \
    } while (0)

        ROPE_ST(c00, 0, 0); ROPE_ST(c01, 0, 1); ROPE_ST(c02, 0, 2); ROPE_ST(c03, 0, 3);
        ROPE_ST(c10, 1, 0); ROPE_ST(c11, 1, 1); ROPE_ST(c12, 1, 2); ROPE_ST(c13, 1, 3);
        ROPE_ST(c20, 2, 0); ROPE_ST(c21, 2, 1); ROPE_ST(c22, 2, 2); ROPE_ST(c23, 2, 3);
        ROPE_ST(c30, 3, 0); ROPE_ST(c31, 3, 1); ROPE_ST(c32, 3, 2); ROPE_ST(c33, 3, 3);
    } else {
        __syncthreads();   // As/Bs done; reuse smem as vstage[d][s], stride VST

#define VST_ACC(accv, MTc, NTc) do {                                                   \
        int dl = wn + (NTc) * 16 + l16;                                                \
        int base = dl * VST + wm + (MTc) * 16 + quad * 4;                              \
        smem[base + 0] = f2bf(accv[0]); smem[base + 1] = f2bf(accv[1]);                \
        smem[base + 2] = f2bf(accv[2]); smem[base + 3] = f2bf(accv[3]);                \
    } while (0)

        VST_ACC(c00, 0, 0); VST_ACC(c01, 0, 1); VST_ACC(c02, 0, 2); VST_ACC(c03, 0, 3);
        VST_ACC(c10, 1, 0); VST_ACC(c11, 1, 1); VST_ACC(c12, 1, 2); VST_ACC(c13, 1, 3);
        VST_ACC(c20, 2, 0); VST_ACC(c21, 2, 1); VST_ACC(c22, 2, 2); VST_ACC(c23, 2, 3);
        VST_ACC(c30, 3, 0); VST_ACC(c31, 3, 1); VST_ACC(c32, 3, 2); VST_ACC(c33, 3, 3);
        __syncthreads();
        int dl = tid >> 1, sh = (tid & 1) * 64;
        int vcol = (n0 - 2048) + dl;          // 0..1023
        int h = vcol >> 6, dd = vcol & 63;
        int b = m0 >> 11, s0 = m0 & (S_LEN - 1);
        unsigned short* dst = vt + (((size_t)(b * NH + h) * DK + dd) * S_LEN + s0 + sh);
        const unsigned short* src = smem + dl * VST + sh;
#pragma unroll
        for (int i = 0; i < 64; i += 8)
            *(bf16x8*)&dst[i] = *(const bf16x8*)&src[i];
    }
}

// ---------------------------------------------------------------------------
// Out projection GEMM: C_fp32 = A_bf16 @ W_bf16^T.
// ---------------------------------------------------------------------------
__global__ __launch_bounds__(256) void gemm_out(const unsigned short* __restrict__ A,
                                                const unsigned short* __restrict__ W,
                                                float* __restrict__ C)
{
    __shared__ __align__(16) unsigned short As[128 * LDSP];
    __shared__ __align__(16) unsigned short Bs[128 * LDSP];
    const int tid  = threadIdx.x;
    const int wave = tid >> 6;
    const int lane = tid & 63;
    const int quad = lane >> 4;
    const int l16  = lane & 15;
    const int m0 = blockIdx.y * 128;
    const int n0 = blockIdx.x * 128;
    const int wm = (wave >> 1) * 64;
    const int wn = (wave & 1) * 64;

    GEMM_MAIN(A, W, 1024, 1024)

#define OUT_ST(accv, MTc, NTc) do {                                                    \
    int col = n0 + wn + (NTc) * 16 + l16;                                              \
    int rowb = m0 + wm + (MTc) * 16 + quad * 4;                                        \
    C[(size_t)(rowb + 0) * 1024 + col] = accv[0];                                      \
    C[(size_t)(rowb + 1) * 1024 + col] = accv[1];                                      \
    C[(size_t)(rowb + 2) * 1024 + col] = accv[2];                                      \
    C[(size_t)(rowb + 3) * 1024 + col] = accv[3];                                      \
} while (0)

    OUT_ST(c00, 0, 0); OUT_ST(c01, 0, 1); OUT_ST(c02, 0, 2); OUT_ST(c03, 0, 3);
    OUT_ST(c10, 1, 0); OUT_ST(c11, 1, 1); OUT_ST(c12, 1, 2); OUT_ST(c13, 1, 3);
    OUT_ST(c20, 2, 0); OUT_ST(c21, 2, 1); OUT_ST(c22, 2, 2); OUT_ST(c23, 2, 3);
    OUT_ST(c30, 3, 0); OUT_ST(c31, 3, 1); OUT_ST(c32, 3, 2); OUT_ST(c33, 3, 3);
}

// ---------------------------------------------------------------------------
// Flash attention, causal, soft-cap 50*tanh(s/50).
// Soft-cap bounds scores -> no online max / rescale (validated earlier).
// One wave = 16 q rows; 64-key chunks; per-wave P buffer in LDS.
//
// ROUND 0: causal load balance — block p handles qblk p AND 31-p (33 chunks).
// ROUND 1: K-reg prefetch spilled (REVERTED). ROUND 2: XCD swizzle cut FETCH
//   10x but L2-hotspot contention cost 20% (REVERTED).
// ROUND 3: block-cooperative K/V staging via global_load_lds, double-
//   buffered, XOR-swizzled fragment reads: 312 -> 150 us, VALUBusy 69%.
// ROUND 4: softmax VALU diet (kernel now VALU-issue-bound, MfmaUtil 10%):
//   (a) cap pre-scale folded into Q scale (gemm_fused) — kills per-score mul
//   (b) exp2(c2*(1-2w)) -> exp2(fma(w,-2c2,c2)) — kills per-score mul
//   (c) P->bf16 via v_cvt_pk_bf16_f32 (2 scores/instr, RNE) vs 3-op f2bf
//   (d) l-sum via ones-column MFMA on the idle matrix pipe — kills l-adds
//       and the epilogue shuffle-reduce; l now sums exactly the bf16 P that
//       PV consumes.  ~128 -> ~48 VALU per chunk-wave.
// ---------------------------------------------------------------------------
#define PPL 72   // P-row stride in LDS (64 keys + 8 pad)

__global__ __launch_bounds__(256) void attn_fwd(const unsigned short* __restrict__ qr,
                                                const unsigned short* __restrict__ kr,
                                                const unsigned short* __restrict__ vt,
                                                unsigned short* __restrict__ aout)
{
    __shared__ __align__(16) unsigned short kvs[2][2][4096]; // [buf][K|V][64x64]
    __shared__ __align__(16) unsigned short plds[4][16 * PPL];
    int blk  = blockIdx.x;                // 32 bh x 16 pair-ids = 1024
    int pr   = blk & 15;
    int bh   = blk >> 4;
    int b    = bh >> 4, h = bh & 15;
    int wave = threadIdx.x >> 6;
    int lane = threadIdx.x & 63;
    int quad = lane >> 4, l16 = lane & 15;

    const unsigned short* kbase = kr + (size_t)bh * S_LEN * DK;
    const unsigned short* vbase = vt + (size_t)bh * DK * S_LEN;
    unsigned short* pw = &plds[wave][0];

    // B-fragment of all-ones (bf16 1.0 = 0x3F80) for the l-sum MFMA.
    u16x8 onesu = {0x3F80,0x3F80,0x3F80,0x3F80,0x3F80,0x3F80,0x3F80,0x3F80};
    bf16x8 vones = *(bf16x8*)&onesu;

    // ---- staging geometry (per-thread constants) ----
    const int lam3  = lane >> 3;                 // == row & 7
    const int sc3p  = (lane & 7) ^ lam3;         // source col for this lane
    const int strow = wave * 8 + lam3;           // row for r=0 (r=1: +32)
    const int stcol = sc3p * 8;                  // elem offset within row
    // fragment read offset: row=l16+16t, want col=quad -> read col quad^(row&7)
    const int kfA = l16 * 64 + ((quad ^ (l16 & 7)) << 3);

#define STAGE(c_, nb_) do {                                                            \
    const int j0s = (c_) * 64;                                                         \
    unsigned short* kd = &kvs[nb_][0][wave * 512];                                     \
    unsigned short* vd = &kvs[nb_][1][wave * 512];                                     \
    const unsigned short* kg = kbase + (size_t)(j0s + strow) * 64 + stcol;             \
    const unsigned short* vg = vbase + (size_t)strow * S_LEN + j0s + stcol;            \
    __builtin_amdgcn_global_load_lds(                                                  \
        (const __attribute__((address_space(1))) unsigned int*)kg,                     \
        (__attribute__((address_space(3))) unsigned int*)kd, 16, 0, 0);                \
    __builtin_amdgcn_global_load_lds(                                                  \
        (const __attribute__((address_space(1))) unsigned int*)(kg + 32 * 64),         \
        (__attribute__((address_space(3))) unsigned int*)(kd + 2048), 16, 0, 0);       \
    __builtin_amdgcn_global_load_lds(                                                  \
        (const __attribute__((address_space(1))) unsigned int*)vg,                     \
        (__attribute__((address_space(3))) unsigned int*)vd, 16, 0, 0);                \
    __builtin_amdgcn_global_load_lds(                                                  \
        (const __attribute__((address_space(1))) unsigned int*)(vg + 32 * S_LEN),      \
        (__attribute__((address_space(3))) unsigned int*)(vd + 2048), 16, 0, 0);       \
} while (0)

#define QK_LDS(kb_) do {                                                               \
    bf16x8 ka, kb;                                                                     \
    ka = *(const bf16x8*)&(kb_)[kfA];          kb = *(const bf16x8*)&(kb_)[kfA ^ 32];  \
    sc0 = MFMA(qf0, ka, sc0); sc0 = MFMA(qf1, kb, sc0);                                \
    ka = *(const bf16x8*)&(kb_)[kfA + 1024];   kb = *(const bf16x8*)&(kb_)[(kfA + 1024) ^ 32]; \
    sc1 = MFMA(qf0, ka, sc1); sc1 = MFMA(qf1, kb, sc1);                                \
    ka = *(const bf16x8*)&(kb_)[kfA + 2048];   kb = *(const bf16x8*)&(kb_)[(kfA + 2048) ^ 32]; \
    sc2 = MFMA(qf0, ka, sc2); sc2 = MFMA(qf1, kb, sc2);                                \
    ka = *(const bf16x8*)&(kb_)[kfA + 3072];   kb = *(const bf16x8*)&(kb_)[(kfA + 3072) ^ 32]; \
    sc3 = MFMA(qf0, ka, sc3); sc3 = MFMA(qf1, kb, sc3);                                \
} while (0)

// PV + the ones-column l-sum on the matrix pipe
#define PV_LDS(vb_) do {                                                               \
    bf16x8 pf0 = *(const bf16x8*)&pw[l16 * PPL + quad * 8];                            \
    bf16x8 pf1 = *(const bf16x8*)&pw[l16 * PPL + 32 + quad * 8];                       \
    bf16x8 va, vb;                                                                     \
    va = *(const bf16x8*)&(vb_)[kfA];          vb = *(const bf16x8*)&(vb_)[kfA ^ 32];  \
    o0 = MFMA(pf0, va, o0); o0 = MFMA(pf1, vb, o0);                                    \
    va = *(const bf16x8*)&(vb_)[kfA + 1024];   vb = *(const bf16x8*)&(vb_)[(kfA + 1024) ^ 32]; \
    o1 = MFMA(pf0, va, o1); o1 = MFMA(pf1, vb, o1);                                    \
    va = *(const bf16x8*)&(vb_)[kfA + 2048];   vb = *(const bf16x8*)&(vb_)[(kfA + 2048) ^ 32]; \
    o2 = MFMA(pf0, va, o2); o2 = MFMA(pf1, vb, o2);                                    \
    va = *(const bf16x8*)&(vb_)[kfA + 3072];   vb = *(const bf16x8*)&(vb_)[(kfA + 3072) ^ 32]; \
    o3 = MFMA(pf0, va, o3); o3 = MFMA(pf1, vb, o3);                                    \
    o4 = MFMA(pf0, vones, o4); o4 = MFMA(pf1, vones, o4);                              \
} while (0)

// pack 4 p-values to bf16 (RNE) with 2 instrs; write to P row (stride-16 keys)
#define P_STORE(rc, p0_, p1_, p2_, p3_) do {                                           \
    unsigned int r01, r23;                                                             \
    asm("v_cvt_pk_bf16_f32 %0, %1, %2" : "=v"(r01) : "v"(p0_), "v"(p1_));              \
    asm("v_cvt_pk_bf16_f32 %0, %1, %2" : "=v"(r23) : "v"(p2_), "v"(p3_));              \
    int rb = (quad * 4 + (rc)) * PPL + l16;                                            \
    pw[rb]      = (unsigned short)r01;                                                 \
    pw[rb + 16] = (unsigned short)(r01 >> 16);                                         \
    pw[rb + 32] = (unsigned short)r23;                                                 \
    pw[rb + 48] = (unsigned short)(r23 >> 16);                                         \
} while (0)

// unmasked softmax row update (non-diagonal chunks)
#define ROW_UPD_N(rc) do {                                                             \
    float p0 = cap_exp2(sc0[rc]);                                                      \
    float p1 = cap_exp2(sc1[rc]);                                                      \
    float p2 = cap_exp2(sc2[rc]);                                                      \
    float p3 = cap_exp2(sc3[rc]);                                                      \
    P_STORE(rc, p0, p1, p2, p3);                                                       \
} while (0)

// masked softmax row update (diagonal chunk only)
#define ROW_UPD_M(rc) do {                                                             \
    int qrow = q0w + quad * 4 + (rc);                                                  \
    float p0 = (j0 + l16      > qrow) ? 0.f : cap_exp2(sc0[rc]);                       \
    float p1 = (j0 + 16 + l16 > qrow) ? 0.f : cap_exp2(sc1[rc]);                       \
    float p2 = (j0 + 32 + l16 > qrow) ? 0.f : cap_exp2(sc2[rc]);                       \
    float p3 = (j0 + 48 + l16 > qrow) ? 0.f : cap_exp2(sc3[rc]);                       \
    P_STORE(rc, p0, p1, p2, p3);                                                       \
} while (0)

    for (int side = 0; side < 2; ++side) {
        const int qblk = side ? (31 - pr) : pr;   // pairs sum to 33 chunks
        const int q0w  = qblk * 64 + wave * 16;

        const unsigned short* qbase = qr + ((size_t)bh * S_LEN + q0w) * DK;
        bf16x8 qf0 = *(const bf16x8*)&qbase[l16 * DK + quad * 8];
        bf16x8 qf1 = *(const bf16x8*)&qbase[l16 * DK + 32 + quad * 8];

        f32x4 zz = {0.f, 0.f, 0.f, 0.f};
        f32x4 o0 = zz, o1 = zz, o2 = zz, o3 = zz, o4 = zz;

        const int nch = qblk + 1;   // 64-key chunks; uniform across the block

        // prologue: stage chunk 0 into buf 0
        STAGE(0, 0);
        asm volatile("s_waitcnt vmcnt(0)" ::: "memory");
        __syncthreads();
        int cb = 0;

        // ---- unmasked chunks 0 .. nch-2 (stage c+1 while computing c) ----
        for (int c = 0; c < nch - 1; ++c) {
            STAGE(c + 1, cb ^ 1);
            f32x4 sc0 = zz, sc1 = zz, sc2 = zz, sc3 = zz;
            QK_LDS(&kvs[cb][0][0]);
            ROW_UPD_N(0); ROW_UPD_N(1); ROW_UPD_N(2); ROW_UPD_N(3);
            // intra-wave LDS write->read ordering (per-wave P buffer)
            asm volatile("s_waitcnt lgkmcnt(0)" ::: "memory");
            PV_LDS(&kvs[cb][1][0]);
            asm volatile("s_waitcnt vmcnt(0)" ::: "memory");
            __syncthreads();
            cb ^= 1;
        }

        // ---- diagonal chunk (c = nch-1): only place causal compares run ----
        {
            const int j0 = (nch - 1) * 64;
            f32x4 sc0 = zz, sc1 = zz, sc2 = zz, sc3 = zz;
            QK_LDS(&kvs[cb][0][0]);
            ROW_UPD_M(0); ROW_UPD_M(1); ROW_UPD_M(2); ROW_UPD_M(3);
            asm volatile("s_waitcnt lgkmcnt(0)" ::: "memory");
            PV_LDS(&kvs[cb][1][0]);
            __syncthreads();   // protect bufs before next side's prologue
        }

        // ---- output: l comes straight from the ones-MFMA accumulator ----
#define OUT_ROW(rc) do {                                                               \
        int qrow = q0w + quad * 4 + (rc);                                              \
        size_t off = (size_t)(b * S_LEN + qrow) * DM + h * DK + l16;                   \
        float rl = 1.0f / o4[rc];                                                      \
        aout[off +  0] = f2bf(o0[rc] * rl);                                            \
        aout[off + 16] = f2bf(o1[rc] * rl);                                            \
        aout[off + 32] = f2bf(o2[rc] * rl);                                            \
        aout[off + 48] = f2bf(o3[rc] * rl);                                            \
} while (0)

        OUT_ROW(0); OUT_ROW(1); OUT_ROW(2); OUT_ROW(3);
#undef OUT_ROW
    }
}

// ---------------------------------------------------------------------------
extern "C" void kernel_launch(void* const* d_in, const int* in_sizes, int n_in,
                              void* d_out, int out_size, void* d_ws, size_t ws_size,
                              hipStream_t stream)
{
    // identify inputs by element count (robust to ordering)
    const void* x = nullptr; const void* wqkv = nullptr; const void* wout = nullptr;
    for (int i = 0; i < n_in; ++i) {
        if      (in_sizes[i] == 8388608) x    = d_in[i];   // [4,2048,1024]
        else if (in_sizes[i] == 3145728) wqkv = d_in[i];   // [3072,1024]
        else if (in_sizes[i] == 1048576) wout = d_in[i];   // [1024,1024]
    }
    float* out = (float*)d_out;                      // [4,2048,1024] fp32
    unsigned short* ws   = (unsigned short*)d_ws;
    unsigned short* ob16 = (unsigned short*)d_out;   // d_out viewed as bf16 scratch

    // ws (48 MiB + 4 B): qr | kr | aout slots of 8,388,608 bf16 elems each.
    unsigned short* qr     = ws;
    unsigned short* kr     = ws + (size_t)8388608;
    unsigned short* aout   = ws + (size_t)16777216;
    int* flag              = (int*)(ws + (size_t)25165824);
    unsigned short* wqkvbf = aout;   // staged in aout slot; dead before attn writes
    unsigned short* woutbf = qr;     // staged in qr slot AFTER attn (qr then dead)

    // d_out bf16 view: vt [0, 8.4M) | xbf [8.4M, 16.8M); both dead before
    // gemm_out overwrites d_out with fp32 results.
    unsigned short* vt  = ob16;
    unsigned short* xbf = ob16 + (size_t)8388608;

    // 0) input dtype autodetect (bf16 expected; fp32 tolerated)
    detect_f32<<<1, 256, 0, stream>>>((const unsigned short*)x, flag);
    // 1) normalize x and w_qkv to bf16
    norm_bf16<<<4096, 256, 0, stream>>>(x, xbf, 8388608, flag);
    norm_bf16<<<1536, 256, 0, stream>>>(wqkv, wqkvbf, 3145728, flag);
    // 2) fused: qkv GEMM + RoPE(q,k) -> qr/kr [b,h,s,d] (q pre-scaled), v -> vt
    gemm_fused<<<dim3(24, 64), 256, 0, stream>>>(xbf, wqkvbf, qr, kr, vt);
    // 3) causal soft-capped flash attention (LDS-staged dbuf + VALU-diet softmax)
    attn_fwd<<<1024, 256, 0, stream>>>(qr, kr, vt, aout);
    // 4) normalize w_out into the now-dead qr slot
    norm_bf16<<<512, 256, 0, stream>>>(wout, woutbf, 1048576, flag);
    // 5) out_fp32 = aout @ w_out^T  (M=8192, N=1024, K=1024)
    gemm_out<<<dim3(8, 64), 256, 0, stream>>>(aout, woutbf, out);
}

// Round 6
// 340.041 us; speedup vs baseline: 1.6678x; 1.1263x over previous
//
#include <hip/hip_runtime.h>
#include <stdint.h>

#define S_LEN 2048
#define NH    16
#define DK    64
#define DM    1024

typedef __attribute__((ext_vector_type(8))) __bf16 bf16x8;
typedef __attribute__((ext_vector_type(8))) unsigned short u16x8;
typedef __attribute__((ext_vector_type(4))) float  f32x4;

static __device__ __forceinline__ unsigned short f2bf(float f) {
    union { float f; unsigned int u; } v; v.f = f;
    unsigned int r = v.u + 0x7FFFu + ((v.u >> 16) & 1u);
    return (unsigned short)(r >> 16);
}

// exp(50*tanh(s/50)) for PRE-SCALED s' = s*2/(50*ln2):
//   u = 2^s' = e^(2s/50);  w = 1/(u+1);  tanh = 1-2w
//   p = exp2(72.1347*(1-2w)) = exp2(fma(w, -144.2695, 72.1347))
static __device__ __forceinline__ float cap_exp2(float sp) {
    float u = exp2f(sp);
    float w = __builtin_amdgcn_rcpf(u + 1.0f);
    return exp2f(__builtin_fmaf(w, -144.2695040888f, 72.1347520444f));
}

// async global->LDS, 16 B/lane; dest must be wave-uniform base (HW adds lane*16)
#define GLL(src_, dst_) __builtin_amdgcn_global_load_lds(                              \
    (const __attribute__((address_space(1))) unsigned int*)(src_),                     \
    (__attribute__((address_space(3))) unsigned int*)(dst_), 16, 0, 0)

// ---------------------------------------------------------------------------
// Input dtype detector (fp32 low-halves have wild bf16 exponents).
// ---------------------------------------------------------------------------
__global__ void detect_f32(const unsigned short* __restrict__ x, int* __restrict__ flag)
{
    __shared__ int tot;
    if (threadIdx.x == 0) tot = 0;
    __syncthreads();
    int weird = 0;
    for (int i = threadIdx.x; i < 16384; i += 256) {
        int e = (x[i] >> 7) & 0xFF;
        if (e == 0 || e < 87 || e > 167) weird++;
    }
    atomicAdd(&tot, weird);
    __syncthreads();
    if (threadIdx.x == 0) *flag = (tot > 4000) ? 1 : 0;
}

// ---------------------------------------------------------------------------
// Normalize an input buffer to bf16 (copy if bf16, convert if fp32).
// ---------------------------------------------------------------------------
__global__ __launch_bounds__(256) void norm_bf16(const void* __restrict__ src,
                                                 unsigned short* __restrict__ dst,
                                                 int n, const int* __restrict__ flag)
{
    const int isf32 = *flag;
    int i = (blockIdx.x * 256 + threadIdx.x) * 8;
    if (i >= n) return;
    if (isf32) {
        const float* p = (const float*)src + i;
        u16x8 o;
        o[0] = f2bf(p[0]); o[1] = f2bf(p[1]); o[2] = f2bf(p[2]); o[3] = f2bf(p[3]);
        o[4] = f2bf(p[4]); o[5] = f2bf(p[5]); o[6] = f2bf(p[6]); o[7] = f2bf(p[7]);
        *(u16x8*)&dst[i] = o;
    } else {
        *(uint4*)&dst[i] = *(const uint4*)((const unsigned short*)src + i);
    }
}

// ---------------------------------------------------------------------------
// RoPE cos/sin table: tab[s][d2] = (cos, sin)(s * theta^(-d2/32)), 2048x32.
// 512 KB, L2-resident; replaces 25M on-device sincosf calls in gemm_fused.
// ---------------------------------------------------------------------------
__global__ __launch_bounds__(256) void rope_tab(float2* __restrict__ tab)
{
    int e = blockIdx.x * 256 + threadIdx.x;   // 65536 entries
    int s = e >> 5, d2 = e & 31;
    float invf = exp2f(-(float)d2 * 0.41524101186f);
    float sn, cs;
    sincosf((float)s * invf, &sn, &cs);
    tab[e] = make_float2(cs, sn);
}

#define VST  136  // padded s-stride for V transpose staging (128 + 8)

#define MFMA(a, b, c) __builtin_amdgcn_mfma_f32_16x16x32_bf16((a), (b), (c), 0, 0, 0)

// ---------------------------------------------------------------------------
// Shared GEMM mainloop — ROUND 5: global_load_lds staging (m97 pattern).
// Linear LDS [128][32] per tile; 4 gll/thread/K-step; fragment reads use
// granule XOR swizzle  g = quad ^ ((row>>1)&3)  (64 B rows: even/odd lanes
// split bank halves, XOR spreads 4-ways -> 2-way residual = free). The
// INVERSE swizzle is applied on the per-lane global source address; the gll
// LDS destination stays linear (wave-uniform base + lane*16).
// ---------------------------------------------------------------------------
#define GEMM_MAIN(Aptr, Wptr, lda_, ldw_)                                              \
    f32x4 zz = {0.f, 0.f, 0.f, 0.f};                                                   \
    f32x4 c00=zz,c01=zz,c02=zz,c03=zz, c10=zz,c11=zz,c12=zz,c13=zz,                    \
          c20=zz,c21=zz,c22=zz,c23=zz, c30=zz,c31=zz,c32=zz,c33=zz;                    \
    const int strow_ = wave * 16 + (lane >> 2);                                        \
    const int sgr_   = (((lane & 3) ^ ((strow_ >> 1) & 3))) << 3;                      \
    const unsigned short* Ag_ = (Aptr) + (size_t)(m0 + strow_) * (lda_) + sgr_;        \
    const unsigned short* Bg_ = (Wptr) + (size_t)(n0 + strow_) * (ldw_) + sgr_;        \
    unsigned short* Asw_ = As + wave * 512;                                            \
    unsigned short* Bsw_ = Bs + wave * 512;                                            \
    const int kfG_ = ((quad ^ ((l16 >> 1) & 3))) << 3;                                 \
    for (int k0 = 0; k0 < 1024; k0 += 32) {                                            \
        __syncthreads();                                                               \
        GLL(Ag_ + k0,                     Asw_);                                       \
        GLL(Ag_ + k0 + 64 * (size_t)(lda_), Asw_ + 2048);                              \
        GLL(Bg_ + k0,                     Bsw_);                                       \
        GLL(Bg_ + k0 + 64 * (size_t)(ldw_), Bsw_ + 2048);                              \
        asm volatile("s_waitcnt vmcnt(0)" ::: "memory");                               \
        __syncthreads();                                                               \
        bf16x8 a0 = *(const bf16x8*)&As[(wm +  0 + l16) * 32 + kfG_];                  \
        bf16x8 a1 = *(const bf16x8*)&As[(wm + 16 + l16) * 32 + kfG_];                  \
        bf16x8 a2 = *(const bf16x8*)&As[(wm + 32 + l16) * 32 + kfG_];                  \
        bf16x8 a3 = *(const bf16x8*)&As[(wm + 48 + l16) * 32 + kfG_];                  \
        bf16x8 b0 = *(const bf16x8*)&Bs[(wn +  0 + l16) * 32 + kfG_];                  \
        bf16x8 b1 = *(const bf16x8*)&Bs[(wn + 16 + l16) * 32 + kfG_];                  \
        bf16x8 b2 = *(const bf16x8*)&Bs[(wn + 32 + l16) * 32 + kfG_];                  \
        bf16x8 b3 = *(const bf16x8*)&Bs[(wn + 48 + l16) * 32 + kfG_];                  \
        c00 = MFMA(a0, b0, c00); c01 = MFMA(a0, b1, c01);                              \
        c02 = MFMA(a0, b2, c02); c03 = MFMA(a0, b3, c03);                              \
        c10 = MFMA(a1, b0, c10); c11 = MFMA(a1, b1, c11);                              \
        c12 = MFMA(a1, b2, c12); c13 = MFMA(a1, b3, c13);                              \
        c20 = MFMA(a2, b0, c20); c21 = MFMA(a2, b1, c21);                              \
        c22 = MFMA(a2, b2, c22); c23 = MFMA(a2, b3, c23);                              \
        c30 = MFMA(a3, b0, c30); c31 = MFMA(a3, b1, c31);                              \
        c32 = MFMA(a3, b2, c32); c33 = MFMA(a3, b3, c33);                              \
    }

// ---------------------------------------------------------------------------
// Fused QKV GEMM + RoPE/V-transpose epilogue (RoPE now table-driven).
// ---------------------------------------------------------------------------
__global__ __launch_bounds__(256) void gemm_fused(const unsigned short* __restrict__ A,
                                                  const unsigned short* __restrict__ W,
                                                  const float2* __restrict__ tab,
                                                  unsigned short* __restrict__ qr,
                                                  unsigned short* __restrict__ kr,
                                                  unsigned short* __restrict__ vt)
{
    __shared__ __align__(16) unsigned short smem[128 * VST]; // As/Bs union V-stage
    unsigned short* As = smem;
    unsigned short* Bs = smem + 4096;

    const int tid  = threadIdx.x;
    const int wave = tid >> 6;
    const int lane = tid & 63;
    const int quad = lane >> 4;
    const int l16  = lane & 15;
    const int m0 = blockIdx.y * 128;
    const int n0 = blockIdx.x * 128;
    const int wm = (wave >> 1) * 64;
    const int wn = (wave & 1) * 64;

    GEMM_MAIN(A, W, 1024, 1024)

    const int cls = n0 >> 10;   // 0=Q, 1=K, 2=V  (block-uniform)
    if (cls < 2) {
        unsigned short* dst = cls ? kr : qr;
        // Q scale folds 1/sqrt(64) AND the soft-cap exp pre-scale 2/(50*ln2).
        const float qs = cls ? 1.0f : 0.125f * 0.0577078016f;

#define ROPE_R(accv, MTc, rc, even_, h_, d_) do {                                      \
        int row = m0 + wm + (MTc) * 16 + quad * 4 + (rc);                              \
        int s = row & (S_LEN - 1), b = row >> 11;                                      \
        float2 cssn = tab[(s << 5) + ((d_) >> 1)];                                     \
        float own = accv[rc];                                                          \
        float oth = __shfl_xor(own, 1);                                                \
        float res = (even_) ? (own * cssn.x - oth * cssn.y)                            \
                            : (oth * cssn.y + own * cssn.x);                           \
        dst[((size_t)(b * NH + (h_)) * S_LEN + s) * DK + (d_)] = f2bf(res * qs);       \
    } while (0)

#define ROPE_ST(accv, MTc, NTc) do {                                                   \
        int col = (n0 & 1023) + wn + (NTc) * 16 + l16;                                 \
        int h = col >> 6, d = col & 63;                                                \
        int even = !(d & 1);                                                           \
        ROPE_R(accv, MTc, 0, even, h, d);                                              \
        ROPE_R(accv, MTc, 1, even, h, d);                                              \
        ROPE_R(accv, MTc, 2, even, h, d);                                              \
        ROPE_R(accv, MTc, 3, even, h, d);                                              \
    } while (0)

        ROPE_ST(c00, 0, 0); ROPE_ST(c01, 0, 1); ROPE_ST(c02, 0, 2); ROPE_ST(c03, 0, 3);
        ROPE_ST(c10, 1, 0); ROPE_ST(c11, 1, 1); ROPE_ST(c12, 1, 2); ROPE_ST(c13, 1, 3);
        ROPE_ST(c20, 2, 0); ROPE_ST(c21, 2, 1); ROPE_ST(c22, 2, 2); ROPE_ST(c23, 2, 3);
        ROPE_ST(c30, 3, 0); ROPE_ST(c31, 3, 1); ROPE_ST(c32, 3, 2); ROPE_ST(c33, 3, 3);
    } else {
        __syncthreads();   // As/Bs done; reuse smem as vstage[d][s], stride VST

#define VST_ACC(accv, MTc, NTc) do {                                                   \
        int dl = wn + (NTc) * 16 + l16;                                                \
        int base = dl * VST + wm + (MTc) * 16 + quad * 4;                              \
        smem[base + 0] = f2bf(accv[0]); smem[base + 1] = f2bf(accv[1]);                \
        smem[base + 2] = f2bf(accv[2]); smem[base + 3] = f2bf(accv[3]);                \
    } while (0)

        VST_ACC(c00, 0, 0); VST_ACC(c01, 0, 1); VST_ACC(c02, 0, 2); VST_ACC(c03, 0, 3);
        VST_ACC(c10, 1, 0); VST_ACC(c11, 1, 1); VST_ACC(c12, 1, 2); VST_ACC(c13, 1, 3);
        VST_ACC(c20, 2, 0); VST_ACC(c21, 2, 1); VST_ACC(c22, 2, 2); VST_ACC(c23, 2, 3);
        VST_ACC(c30, 3, 0); VST_ACC(c31, 3, 1); VST_ACC(c32, 3, 2); VST_ACC(c33, 3, 3);
        __syncthreads();
        int dl = tid >> 1, sh = (tid & 1) * 64;
        int vcol = (n0 - 2048) + dl;          // 0..1023
        int h = vcol >> 6, dd = vcol & 63;
        int b = m0 >> 11, s0 = m0 & (S_LEN - 1);
        unsigned short* dst = vt + (((size_t)(b * NH + h) * DK + dd) * S_LEN + s0 + sh);
        const unsigned short* src = smem + dl * VST + sh;
#pragma unroll
        for (int i = 0; i < 64; i += 8)
            *(bf16x8*)&dst[i] = *(const bf16x8*)&src[i];
    }
}

// ---------------------------------------------------------------------------
// Out projection GEMM: C_fp32 = A_bf16 @ W_bf16^T.
// ---------------------------------------------------------------------------
__global__ __launch_bounds__(256) void gemm_out(const unsigned short* __restrict__ A,
                                                const unsigned short* __restrict__ W,
                                                float* __restrict__ C)
{
    __shared__ __align__(16) unsigned short As[4096];
    __shared__ __align__(16) unsigned short Bs[4096];
    const int tid  = threadIdx.x;
    const int wave = tid >> 6;
    const int lane = tid & 63;
    const int quad = lane >> 4;
    const int l16  = lane & 15;
    const int m0 = blockIdx.y * 128;
    const int n0 = blockIdx.x * 128;
    const int wm = (wave >> 1) * 64;
    const int wn = (wave & 1) * 64;

    GEMM_MAIN(A, W, 1024, 1024)

#define OUT_ST(accv, MTc, NTc) do {                                                    \
    int col = n0 + wn + (NTc) * 16 + l16;                                              \
    int rowb = m0 + wm + (MTc) * 16 + quad * 4;                                        \
    C[(size_t)(rowb + 0) * 1024 + col] = accv[0];                                      \
    C[(size_t)(rowb + 1) * 1024 + col] = accv[1];                                      \
    C[(size_t)(rowb + 2) * 1024 + col] = accv[2];                                      \
    C[(size_t)(rowb + 3) * 1024 + col] = accv[3];                                      \
} while (0)

    OUT_ST(c00, 0, 0); OUT_ST(c01, 0, 1); OUT_ST(c02, 0, 2); OUT_ST(c03, 0, 3);
    OUT_ST(c10, 1, 0); OUT_ST(c11, 1, 1); OUT_ST(c12, 1, 2); OUT_ST(c13, 1, 3);
    OUT_ST(c20, 2, 0); OUT_ST(c21, 2, 1); OUT_ST(c22, 2, 2); OUT_ST(c23, 2, 3);
    OUT_ST(c30, 3, 0); OUT_ST(c31, 3, 1); OUT_ST(c32, 3, 2); OUT_ST(c33, 3, 3);
}

// ---------------------------------------------------------------------------
// Flash attention, causal, soft-cap 50*tanh(s/50).  (UNCHANGED this round —
// control row for the GEMM overhaul.)
// R0: causal pairing. R3: block-coop K/V staging via gll, dbuf, XOR-swizzle
// (312->150us). R4: softmax VALU diet: pre-scaled scores, fused cap fma,
// cvt_pk_bf16 P-store, ones-column MFMA l-sum (150->136us, VALUBusy 65%).
// ---------------------------------------------------------------------------
#define PPL 72   // P-row stride in LDS (64 keys + 8 pad)

__global__ __launch_bounds__(256) void attn_fwd(const unsigned short* __restrict__ qr,
                                                const unsigned short* __restrict__ kr,
                                                const unsigned short* __restrict__ vt,
                                                unsigned short* __restrict__ aout)
{
    __shared__ __align__(16) unsigned short kvs[2][2][4096]; // [buf][K|V][64x64]
    __shared__ __align__(16) unsigned short plds[4][16 * PPL];
    int blk  = blockIdx.x;                // 32 bh x 16 pair-ids = 1024
    int pr   = blk & 15;
    int bh   = blk >> 4;
    int b    = bh >> 4, h = bh & 15;
    int wave = threadIdx.x >> 6;
    int lane = threadIdx.x & 63;
    int quad = lane >> 4, l16 = lane & 15;

    const unsigned short* kbase = kr + (size_t)bh * S_LEN * DK;
    const unsigned short* vbase = vt + (size_t)bh * DK * S_LEN;
    unsigned short* pw = &plds[wave][0];

    // B-fragment of all-ones (bf16 1.0 = 0x3F80) for the l-sum MFMA.
    u16x8 onesu = {0x3F80,0x3F80,0x3F80,0x3F80,0x3F80,0x3F80,0x3F80,0x3F80};
    bf16x8 vones = *(bf16x8*)&onesu;

    // ---- staging geometry (per-thread constants) ----
    const int lam3  = lane >> 3;                 // == row & 7
    const int sc3p  = (lane & 7) ^ lam3;         // source col for this lane
    const int strow = wave * 8 + lam3;           // row for r=0 (r=1: +32)
    const int stcol = sc3p * 8;                  // elem offset within row
    // fragment read offset: row=l16+16t, want col=quad -> read col quad^(row&7)
    const int kfA = l16 * 64 + ((quad ^ (l16 & 7)) << 3);

#define STAGE(c_, nb_) do {                                                            \
    const int j0s = (c_) * 64;                                                         \
    unsigned short* kd = &kvs[nb_][0][wave * 512];                                     \
    unsigned short* vd = &kvs[nb_][1][wave * 512];                                     \
    const unsigned short* kg = kbase + (size_t)(j0s + strow) * 64 + stcol;             \
    const unsigned short* vg = vbase + (size_t)strow * S_LEN + j0s + stcol;            \
    GLL(kg, kd); GLL(kg + 32 * 64, kd + 2048);                                         \
    GLL(vg, vd); GLL(vg + 32 * S_LEN, vd + 2048);                                      \
} while (0)

#define QK_LDS(kb_) do {                                                               \
    bf16x8 ka, kb;                                                                     \
    ka = *(const bf16x8*)&(kb_)[kfA];          kb = *(const bf16x8*)&(kb_)[kfA ^ 32];  \
    sc0 = MFMA(qf0, ka, sc0); sc0 = MFMA(qf1, kb, sc0);                                \
    ka = *(const bf16x8*)&(kb_)[kfA + 1024];   kb = *(const bf16x8*)&(kb_)[(kfA + 1024) ^ 32]; \
    sc1 = MFMA(qf0, ka, sc1); sc1 = MFMA(qf1, kb, sc1);                                \
    ka = *(const bf16x8*)&(kb_)[kfA + 2048];   kb = *(const bf16x8*)&(kb_)[(kfA + 2048) ^ 32]; \
    sc2 = MFMA(qf0, ka, sc2); sc2 = MFMA(qf1, kb, sc2);                                \
    ka = *(const bf16x8*)&(kb_)[kfA + 3072];   kb = *(const bf16x8*)&(kb_)[(kfA + 3072) ^ 32]; \
    sc3 = MFMA(qf0, ka, sc3); sc3 = MFMA(qf1, kb, sc3);                                \
} while (0)

// PV + the ones-column l-sum on the matrix pipe
#define PV_LDS(vb_) do {                                                               \
    bf16x8 pf0 = *(const bf16x8*)&pw[l16 * PPL + quad * 8];                            \
    bf16x8 pf1 = *(const bf16x8*)&pw[l16 * PPL + 32 + quad * 8];                       \
    bf16x8 va, vb;                                                                     \
    va = *(const bf16x8*)&(vb_)[kfA];          vb = *(const bf16x8*)&(vb_)[kfA ^ 32];  \
    o0 = MFMA(pf0, va, o0); o0 = MFMA(pf1, vb, o0);                                    \
    va = *(const bf16x8*)&(vb_)[kfA + 1024];   vb = *(const bf16x8*)&(vb_)[(kfA + 1024) ^ 32]; \
    o1 = MFMA(pf0, va, o1); o1 = MFMA(pf1, vb, o1);                                    \
    va = *(const bf16x8*)&(vb_)[kfA + 2048];   vb = *(const bf16x8*)&(vb_)[(kfA + 2048) ^ 32]; \
    o2 = MFMA(pf0, va, o2); o2 = MFMA(pf1, vb, o2);                                    \
    va = *(const bf16x8*)&(vb_)[kfA + 3072];   vb = *(const bf16x8*)&(vb_)[(kfA + 3072) ^ 32]; \
    o3 = MFMA(pf0, va, o3); o3 = MFMA(pf1, vb, o3);                                    \
    o4 = MFMA(pf0, vones, o4); o4 = MFMA(pf1, vones, o4);                              \
} while (0)

// pack 4 p-values to bf16 (RNE) with 2 instrs; write to P row (stride-16 keys)
#define P_STORE(rc, p0_, p1_, p2_, p3_) do {                                           \
    unsigned int r01, r23;                                                             \
    asm("v_cvt_pk_bf16_f32 %0, %1, %2" : "=v"(r01) : "v"(p0_), "v"(p1_));              \
    asm("v_cvt_pk_bf16_f32 %0, %1, %2" : "=v"(r23) : "v"(p2_), "v"(p3_));              \
    int rb = (quad * 4 + (rc)) * PPL + l16;                                            \
    pw[rb]      = (unsigned short)r01;                                                 \
    pw[rb + 16] = (unsigned short)(r01 >> 16);                                         \
    pw[rb + 32] = (unsigned short)r23;                                                 \
    pw[rb + 48] = (unsigned short)(r23 >> 16);                                         \
} while (0)

// unmasked softmax row update (non-diagonal chunks)
#define ROW_UPD_N(rc) do {                                                             \
    float p0 = cap_exp2(sc0[rc]);                                                      \
    float p1 = cap_exp2(sc1[rc]);                                                      \
    float p2 = cap_exp2(sc2[rc]);                                                      \
    float p3 = cap_exp2(sc3[rc]);                                                      \
    P_STORE(rc, p0, p1, p2, p3);                                                       \
} while (0)

// masked softmax row update (diagonal chunk only)
#define ROW_UPD_M(rc) do {                                                             \
    int qrow = q0w + quad * 4 + (rc);                                                  \
    float p0 = (j0 + l16      > qrow) ? 0.f : cap_exp2(sc0[rc]);                       \
    float p1 = (j0 + 16 + l16 > qrow) ? 0.f : cap_exp2(sc1[rc]);                       \
    float p2 = (j0 + 32 + l16 > qrow) ? 0.f : cap_exp2(sc2[rc]);                       \
    float p3 = (j0 + 48 + l16 > qrow) ? 0.f : cap_exp2(sc3[rc]);                       \
    P_STORE(rc, p0, p1, p2, p3);                                                       \
} while (0)

    for (int side = 0; side < 2; ++side) {
        const int qblk = side ? (31 - pr) : pr;   // pairs sum to 33 chunks
        const int q0w  = qblk * 64 + wave * 16;

        const unsigned short* qbase = qr + ((size_t)bh * S_LEN + q0w) * DK;
        bf16x8 qf0 = *(const bf16x8*)&qbase[l16 * DK + quad * 8];
        bf16x8 qf1 = *(const bf16x8*)&qbase[l16 * DK + 32 + quad * 8];

        f32x4 zz = {0.f, 0.f, 0.f, 0.f};
        f32x4 o0 = zz, o1 = zz, o2 = zz, o3 = zz, o4 = zz;

        const int nch = qblk + 1;   // 64-key chunks; uniform across the block

        // prologue: stage chunk 0 into buf 0
        STAGE(0, 0);
        asm volatile("s_waitcnt vmcnt(0)" ::: "memory");
        __syncthreads();
        int cb = 0;

        // ---- unmasked chunks 0 .. nch-2 (stage c+1 while computing c) ----
        for (int c = 0; c < nch - 1; ++c) {
            STAGE(c + 1, cb ^ 1);
            f32x4 sc0 = zz, sc1 = zz, sc2 = zz, sc3 = zz;
            QK_LDS(&kvs[cb][0][0]);
            ROW_UPD_N(0); ROW_UPD_N(1); ROW_UPD_N(2); ROW_UPD_N(3);
            // intra-wave LDS write->read ordering (per-wave P buffer)
            asm volatile("s_waitcnt lgkmcnt(0)" ::: "memory");
            PV_LDS(&kvs[cb][1][0]);
            asm volatile("s_waitcnt vmcnt(0)" ::: "memory");
            __syncthreads();
            cb ^= 1;
        }

        // ---- diagonal chunk (c = nch-1): only place causal compares run ----
        {
            const int j0 = (nch - 1) * 64;
            f32x4 sc0 = zz, sc1 = zz, sc2 = zz, sc3 = zz;
            QK_LDS(&kvs[cb][0][0]);
            ROW_UPD_M(0); ROW_UPD_M(1); ROW_UPD_M(2); ROW_UPD_M(3);
            asm volatile("s_waitcnt lgkmcnt(0)" ::: "memory");
            PV_LDS(&kvs[cb][1][0]);
            __syncthreads();   // protect bufs before next side's prologue
        }

        // ---- output: l comes straight from the ones-MFMA accumulator ----
#define OUT_ROW(rc) do {                                                               \
        int qrow = q0w + quad * 4 + (rc);                                              \
        size_t off = (size_t)(b * S_LEN + qrow) * DM + h * DK + l16;                   \
        float rl = 1.0f / o4[rc];                                                      \
        aout[off +  0] = f2bf(o0[rc] * rl);                                            \
        aout[off + 16] = f2bf(o1[rc] * rl);                                            \
        aout[off + 32] = f2bf(o2[rc] * rl);                                            \
        aout[off + 48] = f2bf(o3[rc] * rl);                                            \
} while (0)

        OUT_ROW(0); OUT_ROW(1); OUT_ROW(2); OUT_ROW(3);
#undef OUT_ROW
    }
}

// ---------------------------------------------------------------------------
extern "C" void kernel_launch(void* const* d_in, const int* in_sizes, int n_in,
                              void* d_out, int out_size, void* d_ws, size_t ws_size,
                              hipStream_t stream)
{
    // identify inputs by element count (robust to ordering)
    const void* x = nullptr; const void* wqkv = nullptr; const void* wout = nullptr;
    for (int i = 0; i < n_in; ++i) {
        if      (in_sizes[i] == 8388608) x    = d_in[i];   // [4,2048,1024]
        else if (in_sizes[i] == 3145728) wqkv = d_in[i];   // [3072,1024]
        else if (in_sizes[i] == 1048576) wout = d_in[i];   // [1024,1024]
    }
    float* out = (float*)d_out;                      // [4,2048,1024] fp32
    unsigned short* ws   = (unsigned short*)d_ws;
    unsigned short* ob16 = (unsigned short*)d_out;   // d_out viewed as bf16 scratch

    // ws (48 MiB + 4 B): qr | kr | aout slots of 8,388,608 bf16 elems each.
    unsigned short* qr     = ws;
    unsigned short* kr     = ws + (size_t)8388608;
    unsigned short* aout   = ws + (size_t)16777216;
    int* flag              = (int*)(ws + (size_t)25165824);
    unsigned short* wqkvbf = aout;   // staged in aout slot; dead before attn writes
    unsigned short* woutbf = qr;     // staged in qr slot AFTER attn (qr then dead)
    // RoPE table: 512 KB inside the aout slot AFTER wqkvbf (elems +4194304);
    // only live during gemm_fused, overwritten later by attn's aout.
    float2* tab            = (float2*)(ws + (size_t)16777216 + 4194304);

    // d_out bf16 view: vt [0, 8.4M) | xbf [8.4M, 16.8M); both dead before
    // gemm_out overwrites d_out with fp32 results.
    unsigned short* vt  = ob16;
    unsigned short* xbf = ob16 + (size_t)8388608;

    // 0) input dtype autodetect (bf16 expected; fp32 tolerated)
    detect_f32<<<1, 256, 0, stream>>>((const unsigned short*)x, flag);
    // 1) normalize x and w_qkv to bf16; build RoPE cos/sin table
    norm_bf16<<<4096, 256, 0, stream>>>(x, xbf, 8388608, flag);
    norm_bf16<<<1536, 256, 0, stream>>>(wqkv, wqkvbf, 3145728, flag);
    rope_tab<<<256, 256, 0, stream>>>(tab);
    // 2) fused: qkv GEMM (gll staging) + table-RoPE(q,k) -> qr/kr, v -> vt
    gemm_fused<<<dim3(24, 64), 256, 0, stream>>>(xbf, wqkvbf, tab, qr, kr, vt);
    // 3) causal soft-capped flash attention (UNCHANGED — control)
    attn_fwd<<<1024, 256, 0, stream>>>(qr, kr, vt, aout);
    // 4) normalize w_out into the now-dead qr slot
    norm_bf16<<<512, 256, 0, stream>>>(wout, woutbf, 1048576, flag);
    // 5) out_fp32 = aout @ w_out^T  (M=8192, N=1024, K=1024), gll staging
    gemm_out<<<dim3(8, 64), 256, 0, stream>>>(aout, woutbf, out);
}

// Round 7
// 327.375 us; speedup vs baseline: 1.7323x; 1.0387x over previous
//
#include <hip/hip_runtime.h>
#include <stdint.h>

#define S_LEN 2048
#define NH    16
#define DK    64
#define DM    1024

typedef __attribute__((ext_vector_type(8))) __bf16 bf16x8;
typedef __attribute__((ext_vector_type(8))) unsigned short u16x8;
typedef __attribute__((ext_vector_type(4))) float  f32x4;

static __device__ __forceinline__ unsigned short f2bf(float f) {
    union { float f; unsigned int u; } v; v.f = f;
    unsigned int r = v.u + 0x7FFFu + ((v.u >> 16) & 1u);
    return (unsigned short)(r >> 16);
}

// exp(50*tanh(s/50)) for PRE-SCALED s' = s*2/(50*ln2):
//   u = 2^s' = e^(2s/50);  w = 1/(u+1);  tanh = 1-2w
//   p = exp2(72.1347*(1-2w)) = exp2(fma(w, -144.2695, 72.1347))
static __device__ __forceinline__ float cap_exp2(float sp) {
    float u = exp2f(sp);
    float w = __builtin_amdgcn_rcpf(u + 1.0f);
    return exp2f(__builtin_fmaf(w, -144.2695040888f, 72.1347520444f));
}

// async global->LDS, 16 B/lane; dest must be wave-uniform base (HW adds lane*16)
#define GLL(src_, dst_) __builtin_amdgcn_global_load_lds(                              \
    (const __attribute__((address_space(1))) unsigned int*)(src_),                     \
    (__attribute__((address_space(3))) unsigned int*)(dst_), 16, 0, 0)

// ---------------------------------------------------------------------------
// Input dtype detector (fp32 low-halves have wild bf16 exponents).
// ---------------------------------------------------------------------------
__global__ void detect_f32(const unsigned short* __restrict__ x, int* __restrict__ flag)
{
    __shared__ int tot;
    if (threadIdx.x == 0) tot = 0;
    __syncthreads();
    int weird = 0;
    for (int i = threadIdx.x; i < 16384; i += 256) {
        int e = (x[i] >> 7) & 0xFF;
        if (e == 0 || e < 87 || e > 167) weird++;
    }
    atomicAdd(&tot, weird);
    __syncthreads();
    if (threadIdx.x == 0) *flag = (tot > 4000) ? 1 : 0;
}

// ---------------------------------------------------------------------------
// Normalize an input buffer to bf16 (copy if bf16, convert if fp32).
// ---------------------------------------------------------------------------
__global__ __launch_bounds__(256) void norm_bf16(const void* __restrict__ src,
                                                 unsigned short* __restrict__ dst,
                                                 int n, const int* __restrict__ flag)
{
    const int isf32 = *flag;
    int i = (blockIdx.x * 256 + threadIdx.x) * 8;
    if (i >= n) return;
    if (isf32) {
        const float* p = (const float*)src + i;
        u16x8 o;
        o[0] = f2bf(p[0]); o[1] = f2bf(p[1]); o[2] = f2bf(p[2]); o[3] = f2bf(p[3]);
        o[4] = f2bf(p[4]); o[5] = f2bf(p[5]); o[6] = f2bf(p[6]); o[7] = f2bf(p[7]);
        *(u16x8*)&dst[i] = o;
    } else {
        *(uint4*)&dst[i] = *(const uint4*)((const unsigned short*)src + i);
    }
}

// ---------------------------------------------------------------------------
// RoPE cos/sin table: tab[s][d2] = (cos, sin)(s * theta^(-d2/32)), 2048x32.
// 512 KB, L2-resident; replaces 25M on-device sincosf calls in gemm_fused.
// ---------------------------------------------------------------------------
__global__ __launch_bounds__(256) void rope_tab(float2* __restrict__ tab)
{
    int e = blockIdx.x * 256 + threadIdx.x;   // 65536 entries
    int s = e >> 5, d2 = e & 31;
    float invf = exp2f(-(float)d2 * 0.41524101186f);
    float sn, cs;
    sincosf((float)s * invf, &sn, &cs);
    tab[e] = make_float2(cs, sn);
}

#define VST  136  // padded s-stride for V transpose staging (128 + 8)

#define MFMA(a, b, c) __builtin_amdgcn_mfma_f32_16x16x32_bf16((a), (b), (c), 0, 0, 0)

// ---------------------------------------------------------------------------
// Shared GEMM mainloop — ROUND 6: DOUBLE-BUFFERED global_load_lds staging
// (T3 minimal 2-phase). Per K-step: issue GLL for tile k+1 into buf^1,
// compute tile k from buf, then ONE vmcnt(0)+barrier retires the prefetch
// AND protects the swap. Staging latency hides under ds_read+MFMA instead
// of being serially exposed (R5 structure stalled ~500 cy per K-step).
// LDS tiles linear [128][32]; fragment reads use granule XOR swizzle
// g = quad ^ ((row>>1)&3), inverse applied on the per-lane global source
// (gll dest must stay linear — rule #21).  A/B dbuf = 32 KB.
// ---------------------------------------------------------------------------
#define GEMM_MAIN(Aptr, Wptr, lda_, ldw_)                                              \
    f32x4 zz = {0.f, 0.f, 0.f, 0.f};                                                   \
    f32x4 c00=zz,c01=zz,c02=zz,c03=zz, c10=zz,c11=zz,c12=zz,c13=zz,                    \
          c20=zz,c21=zz,c22=zz,c23=zz, c30=zz,c31=zz,c32=zz,c33=zz;                    \
    const int strow_ = wave * 16 + (lane >> 2);                                        \
    const int sgr_   = (((lane & 3) ^ ((strow_ >> 1) & 3))) << 3;                      \
    const unsigned short* Ag_ = (Aptr) + (size_t)(m0 + strow_) * (lda_) + sgr_;        \
    const unsigned short* Bg_ = (Wptr) + (size_t)(n0 + strow_) * (ldw_) + sgr_;        \
    const int kfG_ = ((quad ^ ((l16 >> 1) & 3))) << 3;                                 \
    {                                                                                  \
        unsigned short* Ad_ = As + wave * 512;                                         \
        unsigned short* Bd_ = Bs + wave * 512;                                         \
        GLL(Ag_, Ad_); GLL(Ag_ + 64 * (size_t)(lda_), Ad_ + 2048);                     \
        GLL(Bg_, Bd_); GLL(Bg_ + 64 * (size_t)(ldw_), Bd_ + 2048);                     \
    }                                                                                  \
    __syncthreads();          /* drains vmcnt(0): buf0 ready */                        \
    int cbuf_ = 0;                                                                     \
    for (int k0 = 0; k0 < 1024; k0 += 32) {                                            \
        if (k0 + 32 < 1024) {                                                          \
            unsigned short* Ad_ = As + ((cbuf_ ^ 1) << 12) + wave * 512;               \
            unsigned short* Bd_ = Bs + ((cbuf_ ^ 1) << 12) + wave * 512;               \
            GLL(Ag_ + k0 + 32, Ad_);                                                   \
            GLL(Ag_ + k0 + 32 + 64 * (size_t)(lda_), Ad_ + 2048);                      \
            GLL(Bg_ + k0 + 32, Bd_);                                                   \
            GLL(Bg_ + k0 + 32 + 64 * (size_t)(ldw_), Bd_ + 2048);                      \
        }                                                                              \
        const unsigned short* Ar_ = As + (cbuf_ << 12);                                \
        const unsigned short* Br_ = Bs + (cbuf_ << 12);                                \
        bf16x8 a0 = *(const bf16x8*)&Ar_[(wm +  0 + l16) * 32 + kfG_];                 \
        bf16x8 a1 = *(const bf16x8*)&Ar_[(wm + 16 + l16) * 32 + kfG_];                 \
        bf16x8 a2 = *(const bf16x8*)&Ar_[(wm + 32 + l16) * 32 + kfG_];                 \
        bf16x8 a3 = *(const bf16x8*)&Ar_[(wm + 48 + l16) * 32 + kfG_];                 \
        bf16x8 b0 = *(const bf16x8*)&Br_[(wn +  0 + l16) * 32 + kfG_];                 \
        bf16x8 b1 = *(const bf16x8*)&Br_[(wn + 16 + l16) * 32 + kfG_];                 \
        bf16x8 b2 = *(const bf16x8*)&Br_[(wn + 32 + l16) * 32 + kfG_];                 \
        bf16x8 b3 = *(const bf16x8*)&Br_[(wn + 48 + l16) * 32 + kfG_];                 \
        c00 = MFMA(a0, b0, c00); c01 = MFMA(a0, b1, c01);                              \
        c02 = MFMA(a0, b2, c02); c03 = MFMA(a0, b3, c03);                              \
        c10 = MFMA(a1, b0, c10); c11 = MFMA(a1, b1, c11);                              \
        c12 = MFMA(a1, b2, c12); c13 = MFMA(a1, b3, c13);                              \
        c20 = MFMA(a2, b0, c20); c21 = MFMA(a2, b1, c21);                              \
        c22 = MFMA(a2, b2, c22); c23 = MFMA(a2, b3, c23);                              \
        c30 = MFMA(a3, b0, c30); c31 = MFMA(a3, b1, c31);                              \
        c32 = MFMA(a3, b2, c32); c33 = MFMA(a3, b3, c33);                              \
        __syncthreads();      /* drains prefetch vmcnt + protects swap */              \
        cbuf_ ^= 1;                                                                    \
    }

// ---------------------------------------------------------------------------
// Fused QKV GEMM + RoPE/V-transpose epilogue (table-driven RoPE).
// ---------------------------------------------------------------------------
__global__ __launch_bounds__(256) void gemm_fused(const unsigned short* __restrict__ A,
                                                  const unsigned short* __restrict__ W,
                                                  const float2* __restrict__ tab,
                                                  unsigned short* __restrict__ qr,
                                                  unsigned short* __restrict__ kr,
                                                  unsigned short* __restrict__ vt)
{
    __shared__ __align__(16) unsigned short smem[128 * VST]; // dbuf A/B union V-stage
    unsigned short* As = smem;           // [2][4096]
    unsigned short* Bs = smem + 8192;    // [2][4096]

    const int tid  = threadIdx.x;
    const int wave = tid >> 6;
    const int lane = tid & 63;
    const int quad = lane >> 4;
    const int l16  = lane & 15;
    const int m0 = blockIdx.y * 128;
    const int n0 = blockIdx.x * 128;
    const int wm = (wave >> 1) * 64;
    const int wn = (wave & 1) * 64;

    GEMM_MAIN(A, W, 1024, 1024)

    const int cls = n0 >> 10;   // 0=Q, 1=K, 2=V  (block-uniform)
    if (cls < 2) {
        unsigned short* dst = cls ? kr : qr;
        // Q scale folds 1/sqrt(64) AND the soft-cap exp pre-scale 2/(50*ln2).
        const float qs = cls ? 1.0f : 0.125f * 0.0577078016f;

#define ROPE_R(accv, MTc, rc, even_, h_, d_) do {                                      \
        int row = m0 + wm + (MTc) * 16 + quad * 4 + (rc);                              \
        int s = row & (S_LEN - 1), b = row >> 11;                                      \
        float2 cssn = tab[(s << 5) + ((d_) >> 1)];                                     \
        float own = accv[rc];                                                          \
        float oth = __shfl_xor(own, 1);                                                \
        float res = (even_) ? (own * cssn.x - oth * cssn.y)                            \
                            : (oth * cssn.y + own * cssn.x);                           \
        dst[((size_t)(b * NH + (h_)) * S_LEN + s) * DK + (d_)] = f2bf(res * qs);       \
    } while (0)

#define ROPE_ST(accv, MTc, NTc) do {                                                   \
        int col = (n0 & 1023) + wn + (NTc) * 16 + l16;                                 \
        int h = col >> 6, d = col & 63;                                                \
        int even = !(d & 1);                                                           \
        ROPE_R(accv, MTc, 0, even, h, d);                                              \
        ROPE_R(accv, MTc, 1, even, h, d);                                              \
        ROPE_R(accv, MTc, 2, even, h, d);                                              \
        ROPE_R(accv, MTc, 3, even, h, d);                                              \
    } while (0)

        ROPE_ST(c00, 0, 0); ROPE_ST(c01, 0, 1); ROPE_ST(c02, 0, 2); ROPE_ST(c03, 0, 3);
        ROPE_ST(c10, 1, 0); ROPE_ST(c11, 1, 1); ROPE_ST(c12, 1, 2); ROPE_ST(c13, 1, 3);
        ROPE_ST(c20, 2, 0); ROPE_ST(c21, 2, 1); ROPE_ST(c22, 2, 2); ROPE_ST(c23, 2, 3);
        ROPE_ST(c30, 3, 0); ROPE_ST(c31, 3, 1); ROPE_ST(c32, 3, 2); ROPE_ST(c33, 3, 3);
    } else {
        __syncthreads();   // As/Bs done; reuse smem as vstage[d][s], stride VST

#define VST_ACC(accv, MTc, NTc) do {                                                   \
        int dl = wn + (NTc) * 16 + l16;                                                \
        int base = dl * VST + wm + (MTc) * 16 + quad * 4;                              \
        smem[base + 0] = f2bf(accv[0]); smem[base + 1] = f2bf(accv[1]);                \
        smem[base + 2] = f2bf(accv[2]); smem[base + 3] = f2bf(accv[3]);                \
    } while (0)

        VST_ACC(c00, 0, 0); VST_ACC(c01, 0, 1); VST_ACC(c02, 0, 2); VST_ACC(c03, 0, 3);
        VST_ACC(c10, 1, 0); VST_ACC(c11, 1, 1); VST_ACC(c12, 1, 2); VST_ACC(c13, 1, 3);
        VST_ACC(c20, 2, 0); VST_ACC(c21, 2, 1); VST_ACC(c22, 2, 2); VST_ACC(c23, 2, 3);
        VST_ACC(c30, 3, 0); VST_ACC(c31, 3, 1); VST_ACC(c32, 3, 2); VST_ACC(c33, 3, 3);
        __syncthreads();
        int dl = tid >> 1, sh = (tid & 1) * 64;
        int vcol = (n0 - 2048) + dl;          // 0..1023
        int h = vcol >> 6, dd = vcol & 63;
        int b = m0 >> 11, s0 = m0 & (S_LEN - 1);
        unsigned short* dst = vt + (((size_t)(b * NH + h) * DK + dd) * S_LEN + s0 + sh);
        const unsigned short* src = smem + dl * VST + sh;
#pragma unroll
        for (int i = 0; i < 64; i += 8)
            *(bf16x8*)&dst[i] = *(const bf16x8*)&src[i];
    }
}

// ---------------------------------------------------------------------------
// Out projection GEMM: C_fp32 = A_bf16 @ W_bf16^T.
// ---------------------------------------------------------------------------
__global__ __launch_bounds__(256) void gemm_out(const unsigned short* __restrict__ A,
                                                const unsigned short* __restrict__ W,
                                                float* __restrict__ C)
{
    __shared__ __align__(16) unsigned short As[8192];   // [2][4096]
    __shared__ __align__(16) unsigned short Bs[8192];   // [2][4096]
    const int tid  = threadIdx.x;
    const int wave = tid >> 6;
    const int lane = tid & 63;
    const int quad = lane >> 4;
    const int l16  = lane & 15;
    const int m0 = blockIdx.y * 128;
    const int n0 = blockIdx.x * 128;
    const int wm = (wave >> 1) * 64;
    const int wn = (wave & 1) * 64;

    GEMM_MAIN(A, W, 1024, 1024)

#define OUT_ST(accv, MTc, NTc) do {                                                    \
    int col = n0 + wn + (NTc) * 16 + l16;                                              \
    int rowb = m0 + wm + (MTc) * 16 + quad * 4;                                        \
    C[(size_t)(rowb + 0) * 1024 + col] = accv[0];                                      \
    C[(size_t)(rowb + 1) * 1024 + col] = accv[1];                                      \
    C[(size_t)(rowb + 2) * 1024 + col] = accv[2];                                      \
    C[(size_t)(rowb + 3) * 1024 + col] = accv[3];                                      \
} while (0)

    OUT_ST(c00, 0, 0); OUT_ST(c01, 0, 1); OUT_ST(c02, 0, 2); OUT_ST(c03, 0, 3);
    OUT_ST(c10, 1, 0); OUT_ST(c11, 1, 1); OUT_ST(c12, 1, 2); OUT_ST(c13, 1, 3);
    OUT_ST(c20, 2, 0); OUT_ST(c21, 2, 1); OUT_ST(c22, 2, 2); OUT_ST(c23, 2, 3);
    OUT_ST(c30, 3, 0); OUT_ST(c31, 3, 1); OUT_ST(c32, 3, 2); OUT_ST(c33, 3, 3);
}

// ---------------------------------------------------------------------------
// Flash attention, causal, soft-cap 50*tanh(s/50).  (UNCHANGED — control.)
// R0: causal pairing. R3: block-coop K/V staging via gll, dbuf, XOR-swizzle
// (312->150us). R4: softmax VALU diet (150->136us, VALUBusy 65%).
// ---------------------------------------------------------------------------
#define PPL 72   // P-row stride in LDS (64 keys + 8 pad)

__global__ __launch_bounds__(256) void attn_fwd(const unsigned short* __restrict__ qr,
                                                const unsigned short* __restrict__ kr,
                                                const unsigned short* __restrict__ vt,
                                                unsigned short* __restrict__ aout)
{
    __shared__ __align__(16) unsigned short kvs[2][2][4096]; // [buf][K|V][64x64]
    __shared__ __align__(16) unsigned short plds[4][16 * PPL];
    int blk  = blockIdx.x;                // 32 bh x 16 pair-ids = 1024
    int pr   = blk & 15;
    int bh   = blk >> 4;
    int b    = bh >> 4, h = bh & 15;
    int wave = threadIdx.x >> 6;
    int lane = threadIdx.x & 63;
    int quad = lane >> 4, l16 = lane & 15;

    const unsigned short* kbase = kr + (size_t)bh * S_LEN * DK;
    const unsigned short* vbase = vt + (size_t)bh * DK * S_LEN;
    unsigned short* pw = &plds[wave][0];

    // B-fragment of all-ones (bf16 1.0 = 0x3F80) for the l-sum MFMA.
    u16x8 onesu = {0x3F80,0x3F80,0x3F80,0x3F80,0x3F80,0x3F80,0x3F80,0x3F80};
    bf16x8 vones = *(bf16x8*)&onesu;

    // ---- staging geometry (per-thread constants) ----
    const int lam3  = lane >> 3;                 // == row & 7
    const int sc3p  = (lane & 7) ^ lam3;         // source col for this lane
    const int strow = wave * 8 + lam3;           // row for r=0 (r=1: +32)
    const int stcol = sc3p * 8;                  // elem offset within row
    // fragment read offset: row=l16+16t, want col=quad -> read col quad^(row&7)
    const int kfA = l16 * 64 + ((quad ^ (l16 & 7)) << 3);

#define STAGE(c_, nb_) do {                                                            \
    const int j0s = (c_) * 64;                                                         \
    unsigned short* kd = &kvs[nb_][0][wave * 512];                                     \
    unsigned short* vd = &kvs[nb_][1][wave * 512];                                     \
    const unsigned short* kg = kbase + (size_t)(j0s + strow) * 64 + stcol;             \
    const unsigned short* vg = vbase + (size_t)strow * S_LEN + j0s + stcol;            \
    GLL(kg, kd); GLL(kg + 32 * 64, kd + 2048);                                         \
    GLL(vg, vd); GLL(vg + 32 * S_LEN, vd + 2048);                                      \
} while (0)

#define QK_LDS(kb_) do {                                                               \
    bf16x8 ka, kb;                                                                     \
    ka = *(const bf16x8*)&(kb_)[kfA];          kb = *(const bf16x8*)&(kb_)[kfA ^ 32];  \
    sc0 = MFMA(qf0, ka, sc0); sc0 = MFMA(qf1, kb, sc0);                                \
    ka = *(const bf16x8*)&(kb_)[kfA + 1024];   kb = *(const bf16x8*)&(kb_)[(kfA + 1024) ^ 32]; \
    sc1 = MFMA(qf0, ka, sc1); sc1 = MFMA(qf1, kb, sc1);                                \
    ka = *(const bf16x8*)&(kb_)[kfA + 2048];   kb = *(const bf16x8*)&(kb_)[(kfA + 2048) ^ 32]; \
    sc2 = MFMA(qf0, ka, sc2); sc2 = MFMA(qf1, kb, sc2);                                \
    ka = *(const bf16x8*)&(kb_)[kfA + 3072];   kb = *(const bf16x8*)&(kb_)[(kfA + 3072) ^ 32]; \
    sc3 = MFMA(qf0, ka, sc3); sc3 = MFMA(qf1, kb, sc3);                                \
} while (0)

// PV + the ones-column l-sum on the matrix pipe
#define PV_LDS(vb_) do {                                                               \
    bf16x8 pf0 = *(const bf16x8*)&pw[l16 * PPL + quad * 8];                            \
    bf16x8 pf1 = *(const bf16x8*)&pw[l16 * PPL + 32 + quad * 8];                       \
    bf16x8 va, vb;                                                                     \
    va = *(const bf16x8*)&(vb_)[kfA];          vb = *(const bf16x8*)&(vb_)[kfA ^ 32];  \
    o0 = MFMA(pf0, va, o0); o0 = MFMA(pf1, vb, o0);                                    \
    va = *(const bf16x8*)&(vb_)[kfA + 1024];   vb = *(const bf16x8*)&(vb_)[(kfA + 1024) ^ 32]; \
    o1 = MFMA(pf0, va, o1); o1 = MFMA(pf1, vb, o1);                                    \
    va = *(const bf16x8*)&(vb_)[kfA + 2048];   vb = *(const bf16x8*)&(vb_)[(kfA + 2048) ^ 32]; \
    o2 = MFMA(pf0, va, o2); o2 = MFMA(pf1, vb, o2);                                    \
    va = *(const bf16x8*)&(vb_)[kfA + 3072];   vb = *(const bf16x8*)&(vb_)[(kfA + 3072) ^ 32]; \
    o3 = MFMA(pf0, va, o3); o3 = MFMA(pf1, vb, o3);                                    \
    o4 = MFMA(pf0, vones, o4); o4 = MFMA(pf1, vones, o4);                              \
} while (0)

// pack 4 p-values to bf16 (RNE) with 2 instrs; write to P row (stride-16 keys)
#define P_STORE(rc, p0_, p1_, p2_, p3_) do {                                           \
    unsigned int r01, r23;                                                             \
    asm("v_cvt_pk_bf16_f32 %0, %1, %2" : "=v"(r01) : "v"(p0_), "v"(p1_));              \
    asm("v_cvt_pk_bf16_f32 %0, %1, %2" : "=v"(r23) : "v"(p2_), "v"(p3_));              \
    int rb = (quad * 4 + (rc)) * PPL + l16;                                            \
    pw[rb]      = (unsigned short)r01;                                                 \
    pw[rb + 16] = (unsigned short)(r01 >> 16);                                         \
    pw[rb + 32] = (unsigned short)r23;                                                 \
    pw[rb + 48] = (unsigned short)(r23 >> 16);                                         \
} while (0)

// unmasked softmax row update (non-diagonal chunks)
#define ROW_UPD_N(rc) do {                                                             \
    float p0 = cap_exp2(sc0[rc]);                                                      \
    float p1 = cap_exp2(sc1[rc]);                                                      \
    float p2 = cap_exp2(sc2[rc]);                                                      \
    float p3 = cap_exp2(sc3[rc]);                                                      \
    P_STORE(rc, p0, p1, p2, p3);                                                       \
} while (0)

// masked softmax row update (diagonal chunk only)
#define ROW_UPD_M(rc) do {                                                             \
    int qrow = q0w + quad * 4 + (rc);                                                  \
    float p0 = (j0 + l16      > qrow) ? 0.f : cap_exp2(sc0[rc]);                       \
    float p1 = (j0 + 16 + l16 > qrow) ? 0.f : cap_exp2(sc1[rc]);                       \
    float p2 = (j0 + 32 + l16 > qrow) ? 0.f : cap_exp2(sc2[rc]);                       \
    float p3 = (j0 + 48 + l16 > qrow) ? 0.f : cap_exp2(sc3[rc]);                       \
    P_STORE(rc, p0, p1, p2, p3);                                                       \
} while (0)

    for (int side = 0; side < 2; ++side) {
        const int qblk = side ? (31 - pr) : pr;   // pairs sum to 33 chunks
        const int q0w  = qblk * 64 + wave * 16;

        const unsigned short* qbase = qr + ((size_t)bh * S_LEN + q0w) * DK;
        bf16x8 qf0 = *(const bf16x8*)&qbase[l16 * DK + quad * 8];
        bf16x8 qf1 = *(const bf16x8*)&qbase[l16 * DK + 32 + quad * 8];

        f32x4 zz = {0.f, 0.f, 0.f, 0.f};
        f32x4 o0 = zz, o1 = zz, o2 = zz, o3 = zz, o4 = zz;

        const int nch = qblk + 1;   // 64-key chunks; uniform across the block

        // prologue: stage chunk 0 into buf 0
        STAGE(0, 0);
        asm volatile("s_waitcnt vmcnt(0)" ::: "memory");
        __syncthreads();
        int cb = 0;

        // ---- unmasked chunks 0 .. nch-2 (stage c+1 while computing c) ----
        for (int c = 0; c < nch - 1; ++c) {
            STAGE(c + 1, cb ^ 1);
            f32x4 sc0 = zz, sc1 = zz, sc2 = zz, sc3 = zz;
            QK_LDS(&kvs[cb][0][0]);
            ROW_UPD_N(0); ROW_UPD_N(1); ROW_UPD_N(2); ROW_UPD_N(3);
            // intra-wave LDS write->read ordering (per-wave P buffer)
            asm volatile("s_waitcnt lgkmcnt(0)" ::: "memory");
            PV_LDS(&kvs[cb][1][0]);
            asm volatile("s_waitcnt vmcnt(0)" ::: "memory");
            __syncthreads();
            cb ^= 1;
        }

        // ---- diagonal chunk (c = nch-1): only place causal compares run ----
        {
            const int j0 = (nch - 1) * 64;
            f32x4 sc0 = zz, sc1 = zz, sc2 = zz, sc3 = zz;
            QK_LDS(&kvs[cb][0][0]);
            ROW_UPD_M(0); ROW_UPD_M(1); ROW_UPD_M(2); ROW_UPD_M(3);
            asm volatile("s_waitcnt lgkmcnt(0)" ::: "memory");
            PV_LDS(&kvs[cb][1][0]);
            __syncthreads();   // protect bufs before next side's prologue
        }

        // ---- output: l comes straight from the ones-MFMA accumulator ----
#define OUT_ROW(rc) do {                                                               \
        int qrow = q0w + quad * 4 + (rc);                                              \
        size_t off = (size_t)(b * S_LEN + qrow) * DM + h * DK + l16;                   \
        float rl = 1.0f / o4[rc];                                                      \
        aout[off +  0] = f2bf(o0[rc] * rl);                                            \
        aout[off + 16] = f2bf(o1[rc] * rl);                                            \
        aout[off + 32] = f2bf(o2[rc] * rl);                                            \
        aout[off + 48] = f2bf(o3[rc] * rl);                                            \
} while (0)

        OUT_ROW(0); OUT_ROW(1); OUT_ROW(2); OUT_ROW(3);
#undef OUT_ROW
    }
}

// ---------------------------------------------------------------------------
extern "C" void kernel_launch(void* const* d_in, const int* in_sizes, int n_in,
                              void* d_out, int out_size, void* d_ws, size_t ws_size,
                              hipStream_t stream)
{
    // identify inputs by element count (robust to ordering)
    const void* x = nullptr; const void* wqkv = nullptr; const void* wout = nullptr;
    for (int i = 0; i < n_in; ++i) {
        if      (in_sizes[i] == 8388608) x    = d_in[i];   // [4,2048,1024]
        else if (in_sizes[i] == 3145728) wqkv = d_in[i];   // [3072,1024]
        else if (in_sizes[i] == 1048576) wout = d_in[i];   // [1024,1024]
    }
    float* out = (float*)d_out;                      // [4,2048,1024] fp32
    unsigned short* ws   = (unsigned short*)d_ws;
    unsigned short* ob16 = (unsigned short*)d_out;   // d_out viewed as bf16 scratch

    // ws (48 MiB + 4 B): qr | kr | aout slots of 8,388,608 bf16 elems each.
    unsigned short* qr     = ws;
    unsigned short* kr     = ws + (size_t)8388608;
    unsigned short* aout   = ws + (size_t)16777216;
    int* flag              = (int*)(ws + (size_t)25165824);
    unsigned short* wqkvbf = aout;   // staged in aout slot; dead before attn writes
    unsigned short* woutbf = qr;     // staged in qr slot AFTER attn (qr then dead)
    // RoPE table: 512 KB inside the aout slot AFTER wqkvbf (elems +4194304);
    // only live during gemm_fused, overwritten later by attn's aout.
    float2* tab            = (float2*)(ws + (size_t)16777216 + 4194304);

    // d_out bf16 view: vt [0, 8.4M) | xbf [8.4M, 16.8M); both dead before
    // gemm_out overwrites d_out with fp32 results.
    unsigned short* vt  = ob16;
    unsigned short* xbf = ob16 + (size_t)8388608;

    // 0) input dtype autodetect (bf16 expected; fp32 tolerated)
    detect_f32<<<1, 256, 0, stream>>>((const unsigned short*)x, flag);
    // 1) normalize x and w_qkv to bf16; build RoPE cos/sin table
    norm_bf16<<<4096, 256, 0, stream>>>(x, xbf, 8388608, flag);
    norm_bf16<<<1536, 256, 0, stream>>>(wqkv, wqkvbf, 3145728, flag);
    rope_tab<<<256, 256, 0, stream>>>(tab);
    // 2) fused: qkv GEMM (dbuf gll staging) + table-RoPE(q,k) -> qr/kr, v -> vt
    gemm_fused<<<dim3(24, 64), 256, 0, stream>>>(xbf, wqkvbf, tab, qr, kr, vt);
    // 3) causal soft-capped flash attention (UNCHANGED — control)
    attn_fwd<<<1024, 256, 0, stream>>>(qr, kr, vt, aout);
    // 4) normalize w_out into the now-dead qr slot
    norm_bf16<<<512, 256, 0, stream>>>(wout, woutbf, 1048576, flag);
    // 5) out_fp32 = aout @ w_out^T  (M=8192, N=1024, K=1024), dbuf gll staging
    gemm_out<<<dim3(8, 64), 256, 0, stream>>>(aout, woutbf, out);
}

// Round 8
// 313.080 us; speedup vs baseline: 1.8114x; 1.0457x over previous
//
#include <hip/hip_runtime.h>
#include <stdint.h>

#define S_LEN 2048
#define NH    16
#define DK    64
#define DM    1024

typedef __attribute__((ext_vector_type(8))) __bf16 bf16x8;
typedef __attribute__((ext_vector_type(8))) unsigned short u16x8;
typedef __attribute__((ext_vector_type(4))) float  f32x4;

static __device__ __forceinline__ unsigned short f2bf(float f) {
    union { float f; unsigned int u; } v; v.f = f;
    unsigned int r = v.u + 0x7FFFu + ((v.u >> 16) & 1u);
    return (unsigned short)(r >> 16);
}

// exp(50*tanh(s/50)) for PRE-SCALED s' = s*2/(50*ln2):
//   u = 2^s' = e^(2s/50);  w = 1/(u+1);  tanh = 1-2w
//   p = exp2(72.1347*(1-2w)) = exp2(fma(w, -144.2695, 72.1347))
static __device__ __forceinline__ float cap_exp2(float sp) {
    float u = exp2f(sp);
    float w = __builtin_amdgcn_rcpf(u + 1.0f);
    return exp2f(__builtin_fmaf(w, -144.2695040888f, 72.1347520444f));
}

// async global->LDS, 16 B/lane; dest must be wave-uniform base (HW adds lane*16)
#define GLL(src_, dst_) __builtin_amdgcn_global_load_lds(                              \
    (const __attribute__((address_space(1))) unsigned int*)(src_),                     \
    (__attribute__((address_space(3))) unsigned int*)(dst_), 16, 0, 0)

// ---------------------------------------------------------------------------
// Input dtype detector (fp32 low-halves have wild bf16 exponents).
// ---------------------------------------------------------------------------
__global__ void detect_f32(const unsigned short* __restrict__ x, int* __restrict__ flag)
{
    __shared__ int tot;
    if (threadIdx.x == 0) tot = 0;
    __syncthreads();
    int weird = 0;
    for (int i = threadIdx.x; i < 16384; i += 256) {
        int e = (x[i] >> 7) & 0xFF;
        if (e == 0 || e < 87 || e > 167) weird++;
    }
    atomicAdd(&tot, weird);
    __syncthreads();
    if (threadIdx.x == 0) *flag = (tot > 4000) ? 1 : 0;
}

// ---------------------------------------------------------------------------
// Normalize an input buffer to bf16 (copy if bf16, convert if fp32).
// ---------------------------------------------------------------------------
__global__ __launch_bounds__(256) void norm_bf16(const void* __restrict__ src,
                                                 unsigned short* __restrict__ dst,
                                                 int n, const int* __restrict__ flag)
{
    const int isf32 = *flag;
    int i = (blockIdx.x * 256 + threadIdx.x) * 8;
    if (i >= n) return;
    if (isf32) {
        const float* p = (const float*)src + i;
        u16x8 o;
        o[0] = f2bf(p[0]); o[1] = f2bf(p[1]); o[2] = f2bf(p[2]); o[3] = f2bf(p[3]);
        o[4] = f2bf(p[4]); o[5] = f2bf(p[5]); o[6] = f2bf(p[6]); o[7] = f2bf(p[7]);
        *(u16x8*)&dst[i] = o;
    } else {
        *(uint4*)&dst[i] = *(const uint4*)((const unsigned short*)src + i);
    }
}

// ---------------------------------------------------------------------------
// RoPE cos/sin table: tab[s][d2] = (cos, sin)(s * theta^(-d2/32)), 2048x32.
// 512 KB, L2-resident; replaces 25M on-device sincosf calls in gemm_fused.
// ---------------------------------------------------------------------------
__global__ __launch_bounds__(256) void rope_tab(float2* __restrict__ tab)
{
    int e = blockIdx.x * 256 + threadIdx.x;   // 65536 entries
    int s = e >> 5, d2 = e & 31;
    float invf = exp2f(-(float)d2 * 0.41524101186f);
    float sn, cs;
    sincosf((float)s * invf, &sn, &cs);
    tab[e] = make_float2(cs, sn);
}

#define VST  136  // padded s-stride for V transpose staging (128 + 8)

#define MFMA(a, b, c) __builtin_amdgcn_mfma_f32_16x16x32_bf16((a), (b), (c), 0, 0, 0)

// ---------------------------------------------------------------------------
// Shared GEMM mainloop — ROUND 6: DOUBLE-BUFFERED global_load_lds staging
// (T3 minimal 2-phase).  (UNCHANGED in Round 7 — control.)
// ---------------------------------------------------------------------------
#define GEMM_MAIN(Aptr, Wptr, lda_, ldw_)                                              \
    f32x4 zz = {0.f, 0.f, 0.f, 0.f};                                                   \
    f32x4 c00=zz,c01=zz,c02=zz,c03=zz, c10=zz,c11=zz,c12=zz,c13=zz,                    \
          c20=zz,c21=zz,c22=zz,c23=zz, c30=zz,c31=zz,c32=zz,c33=zz;                    \
    const int strow_ = wave * 16 + (lane >> 2);                                        \
    const int sgr_   = (((lane & 3) ^ ((strow_ >> 1) & 3))) << 3;                      \
    const unsigned short* Ag_ = (Aptr) + (size_t)(m0 + strow_) * (lda_) + sgr_;        \
    const unsigned short* Bg_ = (Wptr) + (size_t)(n0 + strow_) * (ldw_) + sgr_;        \
    const int kfG_ = ((quad ^ ((l16 >> 1) & 3))) << 3;                                 \
    {                                                                                  \
        unsigned short* Ad_ = As + wave * 512;                                         \
        unsigned short* Bd_ = Bs + wave * 512;                                         \
        GLL(Ag_, Ad_); GLL(Ag_ + 64 * (size_t)(lda_), Ad_ + 2048);                     \
        GLL(Bg_, Bd_); GLL(Bg_ + 64 * (size_t)(ldw_), Bd_ + 2048);                     \
    }                                                                                  \
    __syncthreads();          /* drains vmcnt(0): buf0 ready */                        \
    int cbuf_ = 0;                                                                     \
    for (int k0 = 0; k0 < 1024; k0 += 32) {                                            \
        if (k0 + 32 < 1024) {                                                          \
            unsigned short* Ad_ = As + ((cbuf_ ^ 1) << 12) + wave * 512;               \
            unsigned short* Bd_ = Bs + ((cbuf_ ^ 1) << 12) + wave * 512;               \
            GLL(Ag_ + k0 + 32, Ad_);                                                   \
            GLL(Ag_ + k0 + 32 + 64 * (size_t)(lda_), Ad_ + 2048);                      \
            GLL(Bg_ + k0 + 32, Bd_);                                                   \
            GLL(Bg_ + k0 + 32 + 64 * (size_t)(ldw_), Bd_ + 2048);                      \
        }                                                                              \
        const unsigned short* Ar_ = As + (cbuf_ << 12);                                \
        const unsigned short* Br_ = Bs + (cbuf_ << 12);                                \
        bf16x8 a0 = *(const bf16x8*)&Ar_[(wm +  0 + l16) * 32 + kfG_];                 \
        bf16x8 a1 = *(const bf16x8*)&Ar_[(wm + 16 + l16) * 32 + kfG_];                 \
        bf16x8 a2 = *(const bf16x8*)&Ar_[(wm + 32 + l16) * 32 + kfG_];                 \
        bf16x8 a3 = *(const bf16x8*)&Ar_[(wm + 48 + l16) * 32 + kfG_];                 \
        bf16x8 b0 = *(const bf16x8*)&Br_[(wn +  0 + l16) * 32 + kfG_];                 \
        bf16x8 b1 = *(const bf16x8*)&Br_[(wn + 16 + l16) * 32 + kfG_];                 \
        bf16x8 b2 = *(const bf16x8*)&Br_[(wn + 32 + l16) * 32 + kfG_];                 \
        bf16x8 b3 = *(const bf16x8*)&Br_[(wn + 48 + l16) * 32 + kfG_];                 \
        c00 = MFMA(a0, b0, c00); c01 = MFMA(a0, b1, c01);                              \
        c02 = MFMA(a0, b2, c02); c03 = MFMA(a0, b3, c03);                              \
        c10 = MFMA(a1, b0, c10); c11 = MFMA(a1, b1, c11);                              \
        c12 = MFMA(a1, b2, c12); c13 = MFMA(a1, b3, c13);                              \
        c20 = MFMA(a2, b0, c20); c21 = MFMA(a2, b1, c21);                              \
        c22 = MFMA(a2, b2, c22); c23 = MFMA(a2, b3, c23);                              \
        c30 = MFMA(a3, b0, c30); c31 = MFMA(a3, b1, c31);                              \
        c32 = MFMA(a3, b2, c32); c33 = MFMA(a3, b3, c33);                              \
        __syncthreads();      /* drains prefetch vmcnt + protects swap */              \
        cbuf_ ^= 1;                                                                    \
    }

// ---------------------------------------------------------------------------
// Fused QKV GEMM + RoPE/V-transpose epilogue (table-driven RoPE).
// ---------------------------------------------------------------------------
__global__ __launch_bounds__(256) void gemm_fused(const unsigned short* __restrict__ A,
                                                  const unsigned short* __restrict__ W,
                                                  const float2* __restrict__ tab,
                                                  unsigned short* __restrict__ qr,
                                                  unsigned short* __restrict__ kr,
                                                  unsigned short* __restrict__ vt)
{
    __shared__ __align__(16) unsigned short smem[128 * VST]; // dbuf A/B union V-stage
    unsigned short* As = smem;           // [2][4096]
    unsigned short* Bs = smem + 8192;    // [2][4096]

    const int tid  = threadIdx.x;
    const int wave = tid >> 6;
    const int lane = tid & 63;
    const int quad = lane >> 4;
    const int l16  = lane & 15;
    const int m0 = blockIdx.y * 128;
    const int n0 = blockIdx.x * 128;
    const int wm = (wave >> 1) * 64;
    const int wn = (wave & 1) * 64;

    GEMM_MAIN(A, W, 1024, 1024)

    const int cls = n0 >> 10;   // 0=Q, 1=K, 2=V  (block-uniform)
    if (cls < 2) {
        unsigned short* dst = cls ? kr : qr;
        // Q scale folds 1/sqrt(64) AND the soft-cap exp pre-scale 2/(50*ln2).
        const float qs = cls ? 1.0f : 0.125f * 0.0577078016f;

#define ROPE_R(accv, MTc, rc, even_, h_, d_) do {                                      \
        int row = m0 + wm + (MTc) * 16 + quad * 4 + (rc);                              \
        int s = row & (S_LEN - 1), b = row >> 11;                                      \
        float2 cssn = tab[(s << 5) + ((d_) >> 1)];                                     \
        float own = accv[rc];                                                          \
        float oth = __shfl_xor(own, 1);                                                \
        float res = (even_) ? (own * cssn.x - oth * cssn.y)                            \
                            : (oth * cssn.y + own * cssn.x);                           \
        dst[((size_t)(b * NH + (h_)) * S_LEN + s) * DK + (d_)] = f2bf(res * qs);       \
    } while (0)

#define ROPE_ST(accv, MTc, NTc) do {                                                   \
        int col = (n0 & 1023) + wn + (NTc) * 16 + l16;                                 \
        int h = col >> 6, d = col & 63;                                                \
        int even = !(d & 1);                                                           \
        ROPE_R(accv, MTc, 0, even, h, d);                                              \
        ROPE_R(accv, MTc, 1, even, h, d);                                              \
        ROPE_R(accv, MTc, 2, even, h, d);                                              \
        ROPE_R(accv, MTc, 3, even, h, d);                                              \
    } while (0)

        ROPE_ST(c00, 0, 0); ROPE_ST(c01, 0, 1); ROPE_ST(c02, 0, 2); ROPE_ST(c03, 0, 3);
        ROPE_ST(c10, 1, 0); ROPE_ST(c11, 1, 1); ROPE_ST(c12, 1, 2); ROPE_ST(c13, 1, 3);
        ROPE_ST(c20, 2, 0); ROPE_ST(c21, 2, 1); ROPE_ST(c22, 2, 2); ROPE_ST(c23, 2, 3);
        ROPE_ST(c30, 3, 0); ROPE_ST(c31, 3, 1); ROPE_ST(c32, 3, 2); ROPE_ST(c33, 3, 3);
    } else {
        __syncthreads();   // As/Bs done; reuse smem as vstage[d][s], stride VST

#define VST_ACC(accv, MTc, NTc) do {                                                   \
        int dl = wn + (NTc) * 16 + l16;                                                \
        int base = dl * VST + wm + (MTc) * 16 + quad * 4;                              \
        smem[base + 0] = f2bf(accv[0]); smem[base + 1] = f2bf(accv[1]);                \
        smem[base + 2] = f2bf(accv[2]); smem[base + 3] = f2bf(accv[3]);                \
    } while (0)

        VST_ACC(c00, 0, 0); VST_ACC(c01, 0, 1); VST_ACC(c02, 0, 2); VST_ACC(c03, 0, 3);
        VST_ACC(c10, 1, 0); VST_ACC(c11, 1, 1); VST_ACC(c12, 1, 2); VST_ACC(c13, 1, 3);
        VST_ACC(c20, 2, 0); VST_ACC(c21, 2, 1); VST_ACC(c22, 2, 2); VST_ACC(c23, 2, 3);
        VST_ACC(c30, 3, 0); VST_ACC(c31, 3, 1); VST_ACC(c32, 3, 2); VST_ACC(c33, 3, 3);
        __syncthreads();
        int dl = tid >> 1, sh = (tid & 1) * 64;
        int vcol = (n0 - 2048) + dl;          // 0..1023
        int h = vcol >> 6, dd = vcol & 63;
        int b = m0 >> 11, s0 = m0 & (S_LEN - 1);
        unsigned short* dst = vt + (((size_t)(b * NH + h) * DK + dd) * S_LEN + s0 + sh);
        const unsigned short* src = smem + dl * VST + sh;
#pragma unroll
        for (int i = 0; i < 64; i += 8)
            *(bf16x8*)&dst[i] = *(const bf16x8*)&src[i];
    }
}

// ---------------------------------------------------------------------------
// Out projection GEMM: C_fp32 = A_bf16 @ W_bf16^T.
// ---------------------------------------------------------------------------
__global__ __launch_bounds__(256) void gemm_out(const unsigned short* __restrict__ A,
                                                const unsigned short* __restrict__ W,
                                                float* __restrict__ C)
{
    __shared__ __align__(16) unsigned short As[8192];   // [2][4096]
    __shared__ __align__(16) unsigned short Bs[8192];   // [2][4096]
    const int tid  = threadIdx.x;
    const int wave = tid >> 6;
    const int lane = tid & 63;
    const int quad = lane >> 4;
    const int l16  = lane & 15;
    const int m0 = blockIdx.y * 128;
    const int n0 = blockIdx.x * 128;
    const int wm = (wave >> 1) * 64;
    const int wn = (wave & 1) * 64;

    GEMM_MAIN(A, W, 1024, 1024)

#define OUT_ST(accv, MTc, NTc) do {                                                    \
    int col = n0 + wn + (NTc) * 16 + l16;                                              \
    int rowb = m0 + wm + (MTc) * 16 + quad * 4;                                        \
    C[(size_t)(rowb + 0) * 1024 + col] = accv[0];                                      \
    C[(size_t)(rowb + 1) * 1024 + col] = accv[1];                                      \
    C[(size_t)(rowb + 2) * 1024 + col] = accv[2];                                      \
    C[(size_t)(rowb + 3) * 1024 + col] = accv[3];                                      \
} while (0)

    OUT_ST(c00, 0, 0); OUT_ST(c01, 0, 1); OUT_ST(c02, 0, 2); OUT_ST(c03, 0, 3);
    OUT_ST(c10, 1, 0); OUT_ST(c11, 1, 1); OUT_ST(c12, 1, 2); OUT_ST(c13, 1, 3);
    OUT_ST(c20, 2, 0); OUT_ST(c21, 2, 1); OUT_ST(c22, 2, 2); OUT_ST(c23, 2, 3);
    OUT_ST(c30, 3, 0); OUT_ST(c31, 3, 1); OUT_ST(c32, 3, 2); OUT_ST(c33, 3, 3);
}

// ---------------------------------------------------------------------------
// Flash attention, causal, soft-cap 50*tanh(s/50).
// R0: causal pairing. R3: block-coop K/V staging via gll, dbuf, XOR-swizzle
// (312->150us). R4: softmax VALU diet (150->136us).
// ROUND 7: P buffer compacted 16x72 -> 16x64 with the SAME granule-XOR
//   swizzle as K/V (elem = row*64 + (((col>>3)^(row&7))<<3)|(col&7)):
//   reads stay 2-way (free), writes stay 4-way, and LDS drops
//   41984 -> 40960 B = exactly 160KB/4 -> 4 blocks/CU (+33% waves).
//   Counters showed every pipe <20% per-SIMD: residency-bound; LDS was
//   the binding occupancy constraint. P-read addr becomes kfA / kfA^32,
//   identical to the K/V fragment addressing.
// ---------------------------------------------------------------------------
__global__ __launch_bounds__(256) void attn_fwd(const unsigned short* __restrict__ qr,
                                                const unsigned short* __restrict__ kr,
                                                const unsigned short* __restrict__ vt,
                                                unsigned short* __restrict__ aout)
{
    __shared__ __align__(16) unsigned short kvs[2][2][4096]; // [buf][K|V][64x64]
    __shared__ __align__(16) unsigned short plds[4][1024];   // [wave][16x64 swz]
    int blk  = blockIdx.x;                // 32 bh x 16 pair-ids = 1024
    int pr   = blk & 15;
    int bh   = blk >> 4;
    int b    = bh >> 4, h = bh & 15;
    int wave = threadIdx.x >> 6;
    int lane = threadIdx.x & 63;
    int quad = lane >> 4, l16 = lane & 15;

    const unsigned short* kbase = kr + (size_t)bh * S_LEN * DK;
    const unsigned short* vbase = vt + (size_t)bh * DK * S_LEN;
    unsigned short* pw = &plds[wave][0];

    // B-fragment of all-ones (bf16 1.0 = 0x3F80) for the l-sum MFMA.
    u16x8 onesu = {0x3F80,0x3F80,0x3F80,0x3F80,0x3F80,0x3F80,0x3F80,0x3F80};
    bf16x8 vones = *(bf16x8*)&onesu;

    // ---- staging geometry (per-thread constants) ----
    const int lam3  = lane >> 3;                 // == row & 7
    const int sc3p  = (lane & 7) ^ lam3;         // source col for this lane
    const int strow = wave * 8 + lam3;           // row for r=0 (r=1: +32)
    const int stcol = sc3p * 8;                  // elem offset within row
    // fragment read offset: row=l16+16t, want col=quad -> read col quad^(row&7)
    const int kfA = l16 * 64 + ((quad ^ (l16 & 7)) << 3);

#define STAGE(c_, nb_) do {                                                            \
    const int j0s = (c_) * 64;                                                         \
    unsigned short* kd = &kvs[nb_][0][wave * 512];                                     \
    unsigned short* vd = &kvs[nb_][1][wave * 512];                                     \
    const unsigned short* kg = kbase + (size_t)(j0s + strow) * 64 + stcol;             \
    const unsigned short* vg = vbase + (size_t)strow * S_LEN + j0s + stcol;            \
    GLL(kg, kd); GLL(kg + 32 * 64, kd + 2048);                                         \
    GLL(vg, vd); GLL(vg + 32 * S_LEN, vd + 2048);                                      \
} while (0)

#define QK_LDS(kb_) do {                                                               \
    bf16x8 ka, kb;                                                                     \
    ka = *(const bf16x8*)&(kb_)[kfA];          kb = *(const bf16x8*)&(kb_)[kfA ^ 32];  \
    sc0 = MFMA(qf0, ka, sc0); sc0 = MFMA(qf1, kb, sc0);                                \
    ka = *(const bf16x8*)&(kb_)[kfA + 1024];   kb = *(const bf16x8*)&(kb_)[(kfA + 1024) ^ 32]; \
    sc1 = MFMA(qf0, ka, sc1); sc1 = MFMA(qf1, kb, sc1);                                \
    ka = *(const bf16x8*)&(kb_)[kfA + 2048];   kb = *(const bf16x8*)&(kb_)[(kfA + 2048) ^ 32]; \
    sc2 = MFMA(qf0, ka, sc2); sc2 = MFMA(qf1, kb, sc2);                                \
    ka = *(const bf16x8*)&(kb_)[kfA + 3072];   kb = *(const bf16x8*)&(kb_)[(kfA + 3072) ^ 32]; \
    sc3 = MFMA(qf0, ka, sc3); sc3 = MFMA(qf1, kb, sc3);                                \
} while (0)

// PV + the ones-column l-sum on the matrix pipe.  P A-frag reads use the
// SAME swizzled addressing as K/V: pf0 at kfA, pf1 at kfA^32.
#define PV_LDS(vb_) do {                                                               \
    bf16x8 pf0 = *(const bf16x8*)&pw[kfA];                                             \
    bf16x8 pf1 = *(const bf16x8*)&pw[kfA ^ 32];                                        \
    bf16x8 va, vb;                                                                     \
    va = *(const bf16x8*)&(vb_)[kfA];          vb = *(const bf16x8*)&(vb_)[kfA ^ 32];  \
    o0 = MFMA(pf0, va, o0); o0 = MFMA(pf1, vb, o0);                                    \
    va = *(const bf16x8*)&(vb_)[kfA + 1024];   vb = *(const bf16x8*)&(vb_)[(kfA + 1024) ^ 32]; \
    o1 = MFMA(pf0, va, o1); o1 = MFMA(pf1, vb, o1);                                    \
    va = *(const bf16x8*)&(vb_)[kfA + 2048];   vb = *(const bf16x8*)&(vb_)[(kfA + 2048) ^ 32]; \
    o2 = MFMA(pf0, va, o2); o2 = MFMA(pf1, vb, o2);                                    \
    va = *(const bf16x8*)&(vb_)[kfA + 3072];   vb = *(const bf16x8*)&(vb_)[(kfA + 3072) ^ 32]; \
    o3 = MFMA(pf0, va, o3); o3 = MFMA(pf1, vb, o3);                                    \
    o4 = MFMA(pf0, vones, o4); o4 = MFMA(pf1, vones, o4);                              \
} while (0)

// pack 4 p-values to bf16 (RNE); scatter into the granule-swizzled P buffer:
// elem(row,col) = row*64 + (((col>>3)^(row&7))<<3) | (col&7);
// cols are l16, l16+16, l16+32, l16+48 -> col>>3 = (2k)|(l16>>3), col&7 = l16&7.
#define P_STORE(rc, p0_, p1_, p2_, p3_) do {                                           \
    unsigned int r01, r23;                                                             \
    asm("v_cvt_pk_bf16_f32 %0, %1, %2" : "=v"(r01) : "v"(p0_), "v"(p1_));              \
    asm("v_cvt_pk_bf16_f32 %0, %1, %2" : "=v"(r23) : "v"(p2_), "v"(p3_));              \
    const int row_ = quad * 4 + (rc);                                                  \
    const int r7_  = row_ & 7;                                                         \
    const int pb_  = row_ * 64 + (l16 & 7);                                            \
    const int lh_  = l16 >> 3;                                                         \
    pw[pb_ + ((( lh_     ^ r7_) << 3))] = (unsigned short)r01;                         \
    pw[pb_ + (((2 | lh_) ^ r7_) << 3)]  = (unsigned short)(r01 >> 16);                 \
    pw[pb_ + (((4 | lh_) ^ r7_) << 3)]  = (unsigned short)r23;                         \
    pw[pb_ + (((6 | lh_) ^ r7_) << 3)]  = (unsigned short)(r23 >> 16);                 \
} while (0)

// unmasked softmax row update (non-diagonal chunks)
#define ROW_UPD_N(rc) do {                                                             \
    float p0 = cap_exp2(sc0[rc]);                                                      \
    float p1 = cap_exp2(sc1[rc]);                                                      \
    float p2 = cap_exp2(sc2[rc]);                                                      \
    float p3 = cap_exp2(sc3[rc]);                                                      \
    P_STORE(rc, p0, p1, p2, p3);                                                       \
} while (0)

// masked softmax row update (diagonal chunk only)
#define ROW_UPD_M(rc) do {                                                             \
    int qrow = q0w + quad * 4 + (rc);                                                  \
    float p0 = (j0 + l16      > qrow) ? 0.f : cap_exp2(sc0[rc]);                       \
    float p1 = (j0 + 16 + l16 > qrow) ? 0.f : cap_exp2(sc1[rc]);                       \
    float p2 = (j0 + 32 + l16 > qrow) ? 0.f : cap_exp2(sc2[rc]);                       \
    float p3 = (j0 + 48 + l16 > qrow) ? 0.f : cap_exp2(sc3[rc]);                       \
    P_STORE(rc, p0, p1, p2, p3);                                                       \
} while (0)

    for (int side = 0; side < 2; ++side) {
        const int qblk = side ? (31 - pr) : pr;   // pairs sum to 33 chunks
        const int q0w  = qblk * 64 + wave * 16;

        const unsigned short* qbase = qr + ((size_t)bh * S_LEN + q0w) * DK;
        bf16x8 qf0 = *(const bf16x8*)&qbase[l16 * DK + quad * 8];
        bf16x8 qf1 = *(const bf16x8*)&qbase[l16 * DK + 32 + quad * 8];

        f32x4 zz = {0.f, 0.f, 0.f, 0.f};
        f32x4 o0 = zz, o1 = zz, o2 = zz, o3 = zz, o4 = zz;

        const int nch = qblk + 1;   // 64-key chunks; uniform across the block

        // prologue: stage chunk 0 into buf 0
        STAGE(0, 0);
        asm volatile("s_waitcnt vmcnt(0)" ::: "memory");
        __syncthreads();
        int cb = 0;

        // ---- unmasked chunks 0 .. nch-2 (stage c+1 while computing c) ----
        for (int c = 0; c < nch - 1; ++c) {
            STAGE(c + 1, cb ^ 1);
            f32x4 sc0 = zz, sc1 = zz, sc2 = zz, sc3 = zz;
            QK_LDS(&kvs[cb][0][0]);
            ROW_UPD_N(0); ROW_UPD_N(1); ROW_UPD_N(2); ROW_UPD_N(3);
            // intra-wave LDS write->read ordering (per-wave P buffer)
            asm volatile("s_waitcnt lgkmcnt(0)" ::: "memory");
            PV_LDS(&kvs[cb][1][0]);
            asm volatile("s_waitcnt vmcnt(0)" ::: "memory");
            __syncthreads();
            cb ^= 1;
        }

        // ---- diagonal chunk (c = nch-1): only place causal compares run ----
        {
            const int j0 = (nch - 1) * 64;
            f32x4 sc0 = zz, sc1 = zz, sc2 = zz, sc3 = zz;
            QK_LDS(&kvs[cb][0][0]);
            ROW_UPD_M(0); ROW_UPD_M(1); ROW_UPD_M(2); ROW_UPD_M(3);
            asm volatile("s_waitcnt lgkmcnt(0)" ::: "memory");
            PV_LDS(&kvs[cb][1][0]);
            __syncthreads();   // protect bufs before next side's prologue
        }

        // ---- output: l comes straight from the ones-MFMA accumulator ----
#define OUT_ROW(rc) do {                                                               \
        int qrow = q0w + quad * 4 + (rc);                                              \
        size_t off = (size_t)(b * S_LEN + qrow) * DM + h * DK + l16;                   \
        float rl = 1.0f / o4[rc];                                                      \
        aout[off +  0] = f2bf(o0[rc] * rl);                                            \
        aout[off + 16] = f2bf(o1[rc] * rl);                                            \
        aout[off + 32] = f2bf(o2[rc] * rl);                                            \
        aout[off + 48] = f2bf(o3[rc] * rl);                                            \
} while (0)

        OUT_ROW(0); OUT_ROW(1); OUT_ROW(2); OUT_ROW(3);
#undef OUT_ROW
    }
}

// ---------------------------------------------------------------------------
extern "C" void kernel_launch(void* const* d_in, const int* in_sizes, int n_in,
                              void* d_out, int out_size, void* d_ws, size_t ws_size,
                              hipStream_t stream)
{
    // identify inputs by element count (robust to ordering)
    const void* x = nullptr; const void* wqkv = nullptr; const void* wout = nullptr;
    for (int i = 0; i < n_in; ++i) {
        if      (in_sizes[i] == 8388608) x    = d_in[i];   // [4,2048,1024]
        else if (in_sizes[i] == 3145728) wqkv = d_in[i];   // [3072,1024]
        else if (in_sizes[i] == 1048576) wout = d_in[i];   // [1024,1024]
    }
    float* out = (float*)d_out;                      // [4,2048,1024] fp32
    unsigned short* ws   = (unsigned short*)d_ws;
    unsigned short* ob16 = (unsigned short*)d_out;   // d_out viewed as bf16 scratch

    // ws (48 MiB + 4 B): qr | kr | aout slots of 8,388,608 bf16 elems each.
    unsigned short* qr     = ws;
    unsigned short* kr     = ws + (size_t)8388608;
    unsigned short* aout   = ws + (size_t)16777216;
    int* flag              = (int*)(ws + (size_t)25165824);
    unsigned short* wqkvbf = aout;   // staged in aout slot; dead before attn writes
    unsigned short* woutbf = qr;     // staged in qr slot AFTER attn (qr then dead)
    // RoPE table: 512 KB inside the aout slot AFTER wqkvbf (elems +4194304);
    // only live during gemm_fused, overwritten later by attn's aout.
    float2* tab            = (float2*)(ws + (size_t)16777216 + 4194304);

    // d_out bf16 view: vt [0, 8.4M) | xbf [8.4M, 16.8M); both dead before
    // gemm_out overwrites d_out with fp32 results.
    unsigned short* vt  = ob16;
    unsigned short* xbf = ob16 + (size_t)8388608;

    // 0) input dtype autodetect (bf16 expected; fp32 tolerated)
    detect_f32<<<1, 256, 0, stream>>>((const unsigned short*)x, flag);
    // 1) normalize x and w_qkv to bf16; build RoPE cos/sin table
    norm_bf16<<<4096, 256, 0, stream>>>(x, xbf, 8388608, flag);
    norm_bf16<<<1536, 256, 0, stream>>>(wqkv, wqkvbf, 3145728, flag);
    rope_tab<<<256, 256, 0, stream>>>(tab);
    // 2) fused: qkv GEMM (dbuf gll staging) + table-RoPE(q,k) -> qr/kr, v -> vt
    gemm_fused<<<dim3(24, 64), 256, 0, stream>>>(xbf, wqkvbf, tab, qr, kr, vt);
    // 3) causal soft-capped flash attention (4 blocks/CU via compact swz P)
    attn_fwd<<<1024, 256, 0, stream>>>(qr, kr, vt, aout);
    // 4) normalize w_out into the now-dead qr slot
    norm_bf16<<<512, 256, 0, stream>>>(wout, woutbf, 1048576, flag);
    // 5) out_fp32 = aout @ w_out^T  (M=8192, N=1024, K=1024), dbuf gll staging
    gemm_out<<<dim3(8, 64), 256, 0, stream>>>(aout, woutbf, out);
}